// Round 1
// baseline (7075.038 us; speedup 1.0000x reference)
//
#include <hip/hip_runtime.h>

#define M_USERS   200000
#define N_ITEMS   100000
#define NUM_NODES 300000   // M + N
#define DIM       64
#define E_EDGES   4000000

// ---------------------------------------------------------------------------
// 1) init: d_out <- ego = concat(user_emb, item_emb); h <- 0
//    float4 granularity: 16 float4 per row, NUM_NODES*16 total.
// ---------------------------------------------------------------------------
__global__ void init_ego(const float4* __restrict__ user,
                         const float4* __restrict__ item,
                         float4* __restrict__ out,
                         float4* __restrict__ h) {
    int i = blockIdx.x * blockDim.x + threadIdx.x;
    if (i >= NUM_NODES * 16) return;
    float4 v = (i < M_USERS * 16) ? user[i] : item[i - M_USERS * 16];
    out[i] = v;
    h[i] = make_float4(0.f, 0.f, 0.f, 0.f);
}

// ---------------------------------------------------------------------------
// 2) SPMM: dst[row] += val * src[col]   (scatter, fp32 atomics)
//    16 threads per edge, one float4 each.
// ---------------------------------------------------------------------------
__global__ __launch_bounds__(256) void spmm_atomic(
        const int*   __restrict__ rows,
        const int*   __restrict__ cols,
        const float* __restrict__ vals,
        const float4* __restrict__ src,
        float*       __restrict__ dst) {
    int t = blockIdx.x * blockDim.x + threadIdx.x;   // < E*16 = 64M, fits int
    if (t >= E_EDGES * 16) return;
    int e    = t >> 4;
    int part = t & 15;
    int r = rows[e];
    int c = cols[e];
    float v = vals[e];
    float4 x = src[c * 16 + part];
    float* d = dst + (size_t)r * DIM + part * 4;
    atomicAdd(d + 0, x.x * v);
    atomicAdd(d + 1, x.y * v);
    atomicAdd(d + 2, x.z * v);
    atomicAdd(d + 3, x.w * v);
}

// ---------------------------------------------------------------------------
// 3) add: out += h   (acc = ego + h1)
// ---------------------------------------------------------------------------
__global__ void add_inplace(float4* __restrict__ out, const float4* __restrict__ h) {
    int i = blockIdx.x * blockDim.x + threadIdx.x;
    if (i >= NUM_NODES * 16) return;
    float4 a = out[i], b = h[i];
    a.x += b.x; a.y += b.y; a.z += b.z; a.w += b.w;
    out[i] = a;
}

// ---------------------------------------------------------------------------
// 4) fuse: per row r: f1 = acc[r]/3, f2 = hg[r]
//    hdn = tanh([f1,f2] @ W1 + b1); w = softmax(hdn @ W2 + b2)
//    out[r] = w0*f1 + w1*f2      (in-place over acc in d_out)
//    One wave (64 lanes) per row; W1 staged in LDS (32 KB).
// ---------------------------------------------------------------------------
__global__ __launch_bounds__(256) void fuse_kernel(
        float* __restrict__ acc,            // d_out: acc in, fused out
        const float* __restrict__ hg_user,
        const float* __restrict__ hg_item,
        const float* __restrict__ W1,       // (128, 64) row-major
        const float* __restrict__ b1,       // (64)
        const float* __restrict__ W2,       // (64, 2) row-major
        const float* __restrict__ b2,       // (2)
        int nIters, int nWavesTotal) {
    __shared__ float W1s[128 * 64];
    __shared__ float W2s[128];
    __shared__ float b1s[64];
    __shared__ float catS[4][128];

    int tid = threadIdx.x;
    for (int i = tid; i < 128 * 64; i += 256) W1s[i] = W1[i];
    if (tid < 128) W2s[tid] = W2[tid];
    if (tid < 64)  b1s[tid] = b1[tid];
    float b2_0 = b2[0], b2_1 = b2[1];
    __syncthreads();

    int wave = tid >> 6, lane = tid & 63;
    int gwave = blockIdx.x * 4 + wave;

    for (int it = 0; it < nIters; ++it) {
        int row = gwave + it * nWavesTotal;
        bool act = (row < NUM_NODES);
        float f1 = 0.f, f2 = 0.f;
        if (act) {
            f1 = acc[(size_t)row * DIM + lane] * (1.0f / 3.0f);
            f2 = (row < M_USERS)
                 ? hg_user[(size_t)row * DIM + lane]
                 : hg_item[(size_t)(row - M_USERS) * DIM + lane];
            catS[wave][lane]      = f1;
            catS[wave][64 + lane] = f2;
        }
        __syncthreads();   // uniform: all threads, every iteration
        if (act) {
            float h = b1s[lane];
            #pragma unroll 8
            for (int k = 0; k < 128; ++k)
                h = fmaf(catS[wave][k], W1s[k * 64 + lane], h);
            h = tanhf(h);
            float p0 = h * W2s[lane * 2 + 0];
            float p1 = h * W2s[lane * 2 + 1];
            #pragma unroll
            for (int off = 32; off; off >>= 1) {
                p0 += __shfl_xor(p0, off);
                p1 += __shfl_xor(p1, off);
            }
            float l0 = p0 + b2_0, l1 = p1 + b2_1;
            float w0 = 1.0f / (1.0f + __expf(l1 - l0));
            float w1 = 1.0f - w0;
            acc[(size_t)row * DIM + lane] = w0 * f1 + w1 * f2;
        }
        __syncthreads();
    }
}

// ---------------------------------------------------------------------------
extern "C" void kernel_launch(void* const* d_in, const int* in_sizes, int n_in,
                              void* d_out, int out_size, void* d_ws, size_t ws_size,
                              hipStream_t stream) {
    const float* user_emb = (const float*)d_in[0];
    const float* item_emb = (const float*)d_in[1];
    const float* hg_user  = (const float*)d_in[2];
    const float* hg_item  = (const float*)d_in[3];
    const float* adj_vals = (const float*)d_in[4];
    const float* W1       = (const float*)d_in[5];
    const float* b1       = (const float*)d_in[6];
    const float* W2       = (const float*)d_in[7];
    const float* b2       = (const float*)d_in[8];
    const int*   adj_rows = (const int*)d_in[9];
    const int*   adj_cols = (const int*)d_in[10];

    float* out = (float*)d_out;          // acc -> fused, NUM_NODES*64
    float* h   = (float*)d_ws;           // h buffer, NUM_NODES*64 (76.8 MB)

    const int elems4 = NUM_NODES * 16;               // 4.8M float4
    const int initGrid = (elems4 + 255) / 256;       // 18750
    const int spmmGrid = (E_EDGES * 16 + 255) / 256; // 250000

    // 1) out = ego, h = 0
    init_ego<<<initGrid, 256, 0, stream>>>(
        (const float4*)user_emb, (const float4*)item_emb,
        (float4*)out, (float4*)h);

    // 2) h = spmm(ego)            (gather from out, scatter into h)
    spmm_atomic<<<spmmGrid, 256, 0, stream>>>(
        adj_rows, adj_cols, adj_vals, (const float4*)out, h);

    // 3) out += h                 (acc = ego + h1)
    add_inplace<<<initGrid, 256, 0, stream>>>((float4*)out, (const float4*)h);

    // 4) out += spmm(h)           (acc += h2, scatter straight into acc)
    spmm_atomic<<<spmmGrid, 256, 0, stream>>>(
        adj_rows, adj_cols, adj_vals, (const float4*)h, out);

    // 5) fuse in-place on out
    const int fuseBlocks = 2048;
    const int nWavesTotal = fuseBlocks * 4;
    const int nIters = (NUM_NODES + nWavesTotal - 1) / nWavesTotal;
    fuse_kernel<<<fuseBlocks, 256, 0, stream>>>(
        out, hg_user, hg_item, W1, b1, W2, b2, nIters, nWavesTotal);
}

// Round 2
// 1556.732 us; speedup vs baseline: 4.5448x; 4.5448x over previous
//
#include <hip/hip_runtime.h>

#define M_USERS   200000
#define N_ITEMS   100000
#define NUM_NODES 300000   // M + N
#define DIM       64
#define E_EDGES   4000000
#define NPART     ((NUM_NODES + 255) / 256)   // 1172 scan partials

// ===========================================================================
// CSR build: histogram -> block scan -> partial scan -> add offsets -> scatter
// ===========================================================================

__global__ void zero_counts(int* __restrict__ cnt) {
    int i = blockIdx.x * blockDim.x + threadIdx.x;
    if (i < NUM_NODES) cnt[i] = 0;
}

__global__ __launch_bounds__(256) void hist_rows(const int* __restrict__ rows,
                                                 int* __restrict__ cnt) {
    int e = blockIdx.x * blockDim.x + threadIdx.x;
    if (e < E_EDGES) atomicAdd(&cnt[rows[e]], 1);
}

// per-256-block exclusive scan; ex[] gets within-block exclusive prefix,
// part[b] gets block total
__global__ __launch_bounds__(256) void scan_blocks(const int* __restrict__ cnt,
                                                   int* __restrict__ ex,
                                                   int* __restrict__ part) {
    __shared__ int s[256];
    int tid = threadIdx.x;
    int idx = blockIdx.x * 256 + tid;
    int v = (idx < NUM_NODES) ? cnt[idx] : 0;
    s[tid] = v;
    __syncthreads();
    #pragma unroll
    for (int off = 1; off < 256; off <<= 1) {
        int t = (tid >= off) ? s[tid - off] : 0;
        __syncthreads();
        s[tid] += t;
        __syncthreads();
    }
    if (idx < NUM_NODES) ex[idx] = s[tid] - v;
    if (tid == 255) part[blockIdx.x] = s[255];
}

// single wave serial-chunked exclusive scan of the 1172 partials (in-place)
__global__ void scan_partials(int* __restrict__ part, int n) {
    int lane = threadIdx.x;   // blockDim.x == 64
    int carry = 0;
    for (int base = 0; base < n; base += 64) {
        int idx = base + lane;
        int v = (idx < n) ? part[idx] : 0;
        int incl = v;
        #pragma unroll
        for (int off = 1; off < 64; off <<= 1) {
            int t = __shfl_up(incl, off);
            if (lane >= off) incl += t;
        }
        if (idx < n) part[idx] = carry + incl - v;
        carry += __shfl(incl, 63);
    }
}

__global__ void add_offsets(int* __restrict__ start, int* __restrict__ cursor,
                            const int* __restrict__ part) {
    int idx = blockIdx.x * blockDim.x + threadIdx.x;
    if (idx < NUM_NODES) {
        int s = start[idx] + part[idx >> 8];
        start[idx] = s;
        cursor[idx] = s;
    }
}

// pack (col, val) contiguous per destination row
__global__ __launch_bounds__(256) void scatter_edges(const int* __restrict__ rows,
                                                     const int* __restrict__ cols,
                                                     const float* __restrict__ vals,
                                                     int* __restrict__ cursor,
                                                     int2* __restrict__ packed) {
    int e = blockIdx.x * blockDim.x + threadIdx.x;
    if (e < E_EDGES) {
        int r = rows[e];
        int pos = atomicAdd(&cursor[r], 1);
        packed[pos] = make_int2(cols[e], __float_as_int(vals[e]));
    }
}

// ===========================================================================
// SPMM gather: one wave per row, lane = feature.
// MODE 0: h[r] = sum v * ego[c]                     (ego virtual from user/item)
// MODE 1: out[r] = ego[r] + h[r] + sum v * h[c]     (full acc, undivided)
// ===========================================================================
template <int MODE>
__global__ __launch_bounds__(256) void spmm_csr(
        const int*  __restrict__ start,
        const int*  __restrict__ cnt,
        const int2* __restrict__ packed,
        const float* __restrict__ user,
        const float* __restrict__ item,
        float* __restrict__ h,
        float* __restrict__ out) {
    int wave = threadIdx.x >> 6, lane = threadIdx.x & 63;
    int r = blockIdx.x * 4 + wave;
    if (r >= NUM_NODES) return;
    int s = start[r];
    int n = cnt[r];
    float a = 0.f;
    for (int j = s; j < s + n; ++j) {
        int2 p = packed[j];
        int c = p.x;
        float v = __int_as_float(p.y);
        const float* srow;
        if (MODE == 0)
            srow = (c < M_USERS) ? (user + (size_t)c * DIM)
                                 : (item + (size_t)(c - M_USERS) * DIM);
        else
            srow = h + (size_t)c * DIM;
        a = fmaf(v, srow[lane], a);
    }
    if (MODE == 0) {
        h[(size_t)r * DIM + lane] = a;
    } else {
        float ego = (r < M_USERS) ? user[(size_t)r * DIM + lane]
                                  : item[(size_t)(r - M_USERS) * DIM + lane];
        out[(size_t)r * DIM + lane] = ego + h[(size_t)r * DIM + lane] + a;
    }
}

// ===========================================================================
// Fallback path (R1): atomic scatter SPMM — used only if ws_size too small
// ===========================================================================
__global__ void init_ego(const float4* __restrict__ user,
                         const float4* __restrict__ item,
                         float4* __restrict__ out,
                         float4* __restrict__ h) {
    int i = blockIdx.x * blockDim.x + threadIdx.x;
    if (i >= NUM_NODES * 16) return;
    float4 v = (i < M_USERS * 16) ? user[i] : item[i - M_USERS * 16];
    out[i] = v;
    h[i] = make_float4(0.f, 0.f, 0.f, 0.f);
}

__global__ __launch_bounds__(256) void spmm_atomic(
        const int*   __restrict__ rows,
        const int*   __restrict__ cols,
        const float* __restrict__ vals,
        const float4* __restrict__ src,
        float*       __restrict__ dst) {
    int t = blockIdx.x * blockDim.x + threadIdx.x;
    if (t >= E_EDGES * 16) return;
    int e = t >> 4;
    int part = t & 15;
    int r = rows[e];
    int c = cols[e];
    float v = vals[e];
    float4 x = src[c * 16 + part];
    float* d = dst + (size_t)r * DIM + part * 4;
    atomicAdd(d + 0, x.x * v);
    atomicAdd(d + 1, x.y * v);
    atomicAdd(d + 2, x.z * v);
    atomicAdd(d + 3, x.w * v);
}

__global__ void add_inplace(float4* __restrict__ out, const float4* __restrict__ h) {
    int i = blockIdx.x * blockDim.x + threadIdx.x;
    if (i >= NUM_NODES * 16) return;
    float4 a = out[i], b = h[i];
    a.x += b.x; a.y += b.y; a.z += b.z; a.w += b.w;
    out[i] = a;
}

// ===========================================================================
// Fusion MLP: one wave per row; W1 staged in LDS (32 KB)
// ===========================================================================
__global__ __launch_bounds__(256) void fuse_kernel(
        float* __restrict__ acc,            // d_out: acc in, fused out
        const float* __restrict__ hg_user,
        const float* __restrict__ hg_item,
        const float* __restrict__ W1,       // (128, 64) row-major
        const float* __restrict__ b1,       // (64)
        const float* __restrict__ W2,       // (64, 2) row-major
        const float* __restrict__ b2,       // (2)
        int nIters, int nWavesTotal) {
    __shared__ float W1s[128 * 64];
    __shared__ float W2s[128];
    __shared__ float b1s[64];
    __shared__ float catS[4][128];

    int tid = threadIdx.x;
    for (int i = tid; i < 128 * 64; i += 256) W1s[i] = W1[i];
    if (tid < 128) W2s[tid] = W2[tid];
    if (tid < 64)  b1s[tid] = b1[tid];
    float b2_0 = b2[0], b2_1 = b2[1];
    __syncthreads();

    int wave = tid >> 6, lane = tid & 63;
    int gwave = blockIdx.x * 4 + wave;

    for (int it = 0; it < nIters; ++it) {
        int row = gwave + it * nWavesTotal;
        bool act = (row < NUM_NODES);
        float f1 = 0.f, f2 = 0.f;
        if (act) {
            f1 = acc[(size_t)row * DIM + lane] * (1.0f / 3.0f);
            f2 = (row < M_USERS)
                 ? hg_user[(size_t)row * DIM + lane]
                 : hg_item[(size_t)(row - M_USERS) * DIM + lane];
            catS[wave][lane]      = f1;
            catS[wave][64 + lane] = f2;
        }
        __syncthreads();
        if (act) {
            float h = b1s[lane];
            #pragma unroll 8
            for (int k = 0; k < 128; ++k)
                h = fmaf(catS[wave][k], W1s[k * 64 + lane], h);
            h = tanhf(h);
            float p0 = h * W2s[lane * 2 + 0];
            float p1 = h * W2s[lane * 2 + 1];
            #pragma unroll
            for (int off = 32; off; off >>= 1) {
                p0 += __shfl_xor(p0, off);
                p1 += __shfl_xor(p1, off);
            }
            float l0 = p0 + b2_0, l1 = p1 + b2_1;
            float w0 = 1.0f / (1.0f + __expf(l1 - l0));
            float w1 = 1.0f - w0;
            acc[(size_t)row * DIM + lane] = w0 * f1 + w1 * f2;
        }
        __syncthreads();
    }
}

// ===========================================================================
extern "C" void kernel_launch(void* const* d_in, const int* in_sizes, int n_in,
                              void* d_out, int out_size, void* d_ws, size_t ws_size,
                              hipStream_t stream) {
    const float* user_emb = (const float*)d_in[0];
    const float* item_emb = (const float*)d_in[1];
    const float* hg_user  = (const float*)d_in[2];
    const float* hg_item  = (const float*)d_in[3];
    const float* adj_vals = (const float*)d_in[4];
    const float* W1       = (const float*)d_in[5];
    const float* b1       = (const float*)d_in[6];
    const float* W2       = (const float*)d_in[7];
    const float* b2       = (const float*)d_in[8];
    const int*   adj_rows = (const int*)d_in[9];
    const int*   adj_cols = (const int*)d_in[10];

    float* out = (float*)d_out;

    // workspace layout
    char* ws = (char*)d_ws;
    size_t off = 0;
    float* h = (float*)(ws + off);        off += (size_t)NUM_NODES * DIM * 4;   // 76.8 MB
    int* cnt    = (int*)(ws + off);       off += (size_t)NUM_NODES * 4;
    int* start  = (int*)(ws + off);       off += (size_t)NUM_NODES * 4;
    int* cursor = (int*)(ws + off);       off += (size_t)NUM_NODES * 4;
    int* part   = (int*)(ws + off);       off += ((size_t)NPART * 4 + 255) & ~255ull;
    int2* packed = (int2*)(ws + off);     off += (size_t)E_EDGES * 8;           // 32 MB
    const size_t need = off;

    const int nodeGrid = (NUM_NODES + 255) / 256;      // 1172
    const int edgeGrid = (E_EDGES + 255) / 256;        // 15625
    const int rowGrid  = (NUM_NODES + 3) / 4;          // 75000 (4 waves/block)

    if (ws_size >= need) {
        // ---- CSR build ----
        zero_counts<<<nodeGrid, 256, 0, stream>>>(cnt);
        hist_rows<<<edgeGrid, 256, 0, stream>>>(adj_rows, cnt);
        scan_blocks<<<NPART, 256, 0, stream>>>(cnt, start, part);
        scan_partials<<<1, 64, 0, stream>>>(part, NPART);
        add_offsets<<<nodeGrid, 256, 0, stream>>>(start, cursor, part);
        scatter_edges<<<edgeGrid, 256, 0, stream>>>(adj_rows, adj_cols, adj_vals,
                                                    cursor, packed);
        // ---- SPMM passes (gather, no float atomics) ----
        spmm_csr<0><<<rowGrid, 256, 0, stream>>>(start, cnt, packed,
                                                 user_emb, item_emb, h, out);
        spmm_csr<1><<<rowGrid, 256, 0, stream>>>(start, cnt, packed,
                                                 user_emb, item_emb, h, out);
    } else {
        // ---- fallback: R1 atomic path (needs only h) ----
        const int elems4Grid = (NUM_NODES * 16 + 255) / 256;
        const int spmmGrid   = (E_EDGES * 16 + 255) / 256;
        init_ego<<<elems4Grid, 256, 0, stream>>>(
            (const float4*)user_emb, (const float4*)item_emb,
            (float4*)out, (float4*)h);
        spmm_atomic<<<spmmGrid, 256, 0, stream>>>(
            adj_rows, adj_cols, adj_vals, (const float4*)out, h);
        add_inplace<<<elems4Grid, 256, 0, stream>>>((float4*)out, (const float4*)h);
        spmm_atomic<<<spmmGrid, 256, 0, stream>>>(
            adj_rows, adj_cols, adj_vals, (const float4*)h, out);
    }

    // ---- fusion MLP in-place on out ----
    const int fuseBlocks = 2048;
    const int nWavesTotal = fuseBlocks * 4;
    const int nIters = (NUM_NODES + nWavesTotal - 1) / nWavesTotal;
    fuse_kernel<<<fuseBlocks, 256, 0, stream>>>(
        out, hg_user, hg_item, W1, b1, W2, b2, nIters, nWavesTotal);
}

// Round 3
// 1098.863 us; speedup vs baseline: 6.4385x; 1.4167x over previous
//
#include <hip/hip_runtime.h>

#define M_USERS   200000
#define N_ITEMS   100000
#define NUM_NODES 300000   // M + N
#define DIM       64
#define E_EDGES   4000000
#define NPART     ((NUM_NODES + 255) / 256)   // 1172 scan partials

// ===========================================================================
// CSR build: histogram -> block scan -> partial scan -> add offsets -> scatter
// ===========================================================================

__global__ void zero_counts(int* __restrict__ cnt) {
    int i = blockIdx.x * blockDim.x + threadIdx.x;
    if (i < NUM_NODES) cnt[i] = 0;
}

__global__ __launch_bounds__(256) void hist_rows(const int* __restrict__ rows,
                                                 int* __restrict__ cnt) {
    int e = blockIdx.x * blockDim.x + threadIdx.x;
    if (e < E_EDGES) atomicAdd(&cnt[rows[e]], 1);
}

// per-256-block exclusive scan; ex[] gets within-block exclusive prefix,
// part[b] gets block total
__global__ __launch_bounds__(256) void scan_blocks(const int* __restrict__ cnt,
                                                   int* __restrict__ ex,
                                                   int* __restrict__ part) {
    __shared__ int s[256];
    int tid = threadIdx.x;
    int idx = blockIdx.x * 256 + tid;
    int v = (idx < NUM_NODES) ? cnt[idx] : 0;
    s[tid] = v;
    __syncthreads();
    #pragma unroll
    for (int off = 1; off < 256; off <<= 1) {
        int t = (tid >= off) ? s[tid - off] : 0;
        __syncthreads();
        s[tid] += t;
        __syncthreads();
    }
    if (idx < NUM_NODES) ex[idx] = s[tid] - v;
    if (tid == 255) part[blockIdx.x] = s[255];
}

// single wave serial-chunked exclusive scan of the 1172 partials (in-place)
__global__ void scan_partials(int* __restrict__ part, int n) {
    int lane = threadIdx.x;   // blockDim.x == 64
    int carry = 0;
    for (int base = 0; base < n; base += 64) {
        int idx = base + lane;
        int v = (idx < n) ? part[idx] : 0;
        int incl = v;
        #pragma unroll
        for (int off = 1; off < 64; off <<= 1) {
            int t = __shfl_up(incl, off);
            if (lane >= off) incl += t;
        }
        if (idx < n) part[idx] = carry + incl - v;
        carry += __shfl(incl, 63);
    }
}

__global__ void add_offsets(int* __restrict__ start, int* __restrict__ cursor,
                            const int* __restrict__ part) {
    int idx = blockIdx.x * blockDim.x + threadIdx.x;
    if (idx < NUM_NODES) {
        int s = start[idx] + part[idx >> 8];
        start[idx] = s;
        cursor[idx] = s;
    }
}

// pack (col, val) contiguous per destination row
__global__ __launch_bounds__(256) void scatter_edges(const int* __restrict__ rows,
                                                     const int* __restrict__ cols,
                                                     const float* __restrict__ vals,
                                                     int* __restrict__ cursor,
                                                     int2* __restrict__ packed) {
    int e = blockIdx.x * blockDim.x + threadIdx.x;
    if (e < E_EDGES) {
        int r = rows[e];
        int pos = atomicAdd(&cursor[r], 1);
        packed[pos] = make_int2(cols[e], __float_as_int(vals[e]));
    }
}

// ===========================================================================
// SPMM gather: one wave per row; 16 lanes x float4 per row-read,
// 8 edges in flight per iteration (two 4-edge slots).
// MODE 0: h[r] = sum v * ego[c]                   (ego virtual from user/item)
// MODE 1: out[r] = ego[r] + h[r] + sum v * h[c]   (full acc, undivided)
// ===========================================================================
template <int MODE>
__global__ __launch_bounds__(256) void spmm_csr(
        const int*  __restrict__ start,
        const int*  __restrict__ cnt,
        const int2* __restrict__ packed,
        const float4* __restrict__ user4,
        const float4* __restrict__ item4,
        float4* __restrict__ h4,
        float4* __restrict__ out4) {
    int wave = threadIdx.x >> 6, lane = threadIdx.x & 63;
    int r = blockIdx.x * 4 + wave;
    if (r >= NUM_NODES) return;
    int s = start[r];
    int end = s + cnt[r];
    int sub = lane >> 4;      // edge slot 0..3
    int q   = lane & 15;      // float4 index within the 64-float row

    float4 acc = make_float4(0.f, 0.f, 0.f, 0.f);

    for (int j = s; j < end; j += 8) {
        int iA = j + sub;
        int iB = j + 4 + sub;
        int2 pA = (iA < end) ? packed[iA] : make_int2(0, 0);
        int2 pB = (iB < end) ? packed[iB] : make_int2(0, 0);
        const float4* rowA;
        const float4* rowB;
        if (MODE == 0) {
            rowA = (pA.x < M_USERS) ? user4 + (size_t)pA.x * 16
                                    : item4 + (size_t)(pA.x - M_USERS) * 16;
            rowB = (pB.x < M_USERS) ? user4 + (size_t)pB.x * 16
                                    : item4 + (size_t)(pB.x - M_USERS) * 16;
        } else {
            rowA = h4 + (size_t)pA.x * 16;
            rowB = h4 + (size_t)pB.x * 16;
        }
        float4 xA = rowA[q];
        float4 xB = rowB[q];
        float vA = __int_as_float(pA.y);
        float vB = __int_as_float(pB.y);
        acc.x = fmaf(vA, xA.x, acc.x);
        acc.y = fmaf(vA, xA.y, acc.y);
        acc.z = fmaf(vA, xA.z, acc.z);
        acc.w = fmaf(vA, xA.w, acc.w);
        acc.x = fmaf(vB, xB.x, acc.x);
        acc.y = fmaf(vB, xB.y, acc.y);
        acc.z = fmaf(vB, xB.z, acc.z);
        acc.w = fmaf(vB, xB.w, acc.w);
    }

    // reduce the 4 edge slots: lanes {q, q+16, q+32, q+48} hold partials
    acc.x += __shfl_xor(acc.x, 16);
    acc.y += __shfl_xor(acc.y, 16);
    acc.z += __shfl_xor(acc.z, 16);
    acc.w += __shfl_xor(acc.w, 16);
    acc.x += __shfl_xor(acc.x, 32);
    acc.y += __shfl_xor(acc.y, 32);
    acc.z += __shfl_xor(acc.z, 32);
    acc.w += __shfl_xor(acc.w, 32);

    if (lane < 16) {
        size_t o = (size_t)r * 16 + q;
        if (MODE == 0) {
            h4[o] = acc;
        } else {
            float4 ego = (r < M_USERS) ? user4[o]
                                       : item4[(size_t)(r - M_USERS) * 16 + q];
            float4 hh = h4[o];
            float4 res;
            res.x = ego.x + hh.x + acc.x;
            res.y = ego.y + hh.y + acc.y;
            res.z = ego.z + hh.z + acc.z;
            res.w = ego.w + hh.w + acc.w;
            out4[o] = res;
        }
    }
}

// ===========================================================================
// Fallback path (R1): atomic scatter SPMM — used only if ws_size too small
// ===========================================================================
__global__ void init_ego(const float4* __restrict__ user,
                         const float4* __restrict__ item,
                         float4* __restrict__ out,
                         float4* __restrict__ h) {
    int i = blockIdx.x * blockDim.x + threadIdx.x;
    if (i >= NUM_NODES * 16) return;
    float4 v = (i < M_USERS * 16) ? user[i] : item[i - M_USERS * 16];
    out[i] = v;
    h[i] = make_float4(0.f, 0.f, 0.f, 0.f);
}

__global__ __launch_bounds__(256) void spmm_atomic(
        const int*   __restrict__ rows,
        const int*   __restrict__ cols,
        const float* __restrict__ vals,
        const float4* __restrict__ src,
        float*       __restrict__ dst) {
    int t = blockIdx.x * blockDim.x + threadIdx.x;
    if (t >= E_EDGES * 16) return;
    int e = t >> 4;
    int part = t & 15;
    int r = rows[e];
    int c = cols[e];
    float v = vals[e];
    float4 x = src[c * 16 + part];
    float* d = dst + (size_t)r * DIM + part * 4;
    atomicAdd(d + 0, x.x * v);
    atomicAdd(d + 1, x.y * v);
    atomicAdd(d + 2, x.z * v);
    atomicAdd(d + 3, x.w * v);
}

__global__ void add_inplace(float4* __restrict__ out, const float4* __restrict__ h) {
    int i = blockIdx.x * blockDim.x + threadIdx.x;
    if (i >= NUM_NODES * 16) return;
    float4 a = out[i], b = h[i];
    a.x += b.x; a.y += b.y; a.z += b.z; a.w += b.w;
    out[i] = a;
}

// ===========================================================================
// Fusion MLP: one wave per row; W1 staged in LDS (32 KB)
// ===========================================================================
__global__ __launch_bounds__(256) void fuse_kernel(
        float* __restrict__ acc,            // d_out: acc in, fused out
        const float* __restrict__ hg_user,
        const float* __restrict__ hg_item,
        const float* __restrict__ W1,       // (128, 64) row-major
        const float* __restrict__ b1,       // (64)
        const float* __restrict__ W2,       // (64, 2) row-major
        const float* __restrict__ b2,       // (2)
        int nIters, int nWavesTotal) {
    __shared__ float W1s[128 * 64];
    __shared__ float W2s[128];
    __shared__ float b1s[64];
    __shared__ float catS[4][128];

    int tid = threadIdx.x;
    for (int i = tid; i < 128 * 64; i += 256) W1s[i] = W1[i];
    if (tid < 128) W2s[tid] = W2[tid];
    if (tid < 64)  b1s[tid] = b1[tid];
    float b2_0 = b2[0], b2_1 = b2[1];
    __syncthreads();

    int wave = tid >> 6, lane = tid & 63;
    int gwave = blockIdx.x * 4 + wave;

    for (int it = 0; it < nIters; ++it) {
        int row = gwave + it * nWavesTotal;
        bool act = (row < NUM_NODES);
        float f1 = 0.f, f2 = 0.f;
        if (act) {
            f1 = acc[(size_t)row * DIM + lane] * (1.0f / 3.0f);
            f2 = (row < M_USERS)
                 ? hg_user[(size_t)row * DIM + lane]
                 : hg_item[(size_t)(row - M_USERS) * DIM + lane];
            catS[wave][lane]      = f1;
            catS[wave][64 + lane] = f2;
        }
        __syncthreads();
        if (act) {
            float h = b1s[lane];
            #pragma unroll 8
            for (int k = 0; k < 128; ++k)
                h = fmaf(catS[wave][k], W1s[k * 64 + lane], h);
            h = tanhf(h);
            float p0 = h * W2s[lane * 2 + 0];
            float p1 = h * W2s[lane * 2 + 1];
            #pragma unroll
            for (int off = 32; off; off >>= 1) {
                p0 += __shfl_xor(p0, off);
                p1 += __shfl_xor(p1, off);
            }
            float l0 = p0 + b2_0, l1 = p1 + b2_1;
            float w0 = 1.0f / (1.0f + __expf(l1 - l0));
            float w1 = 1.0f - w0;
            acc[(size_t)row * DIM + lane] = w0 * f1 + w1 * f2;
        }
        __syncthreads();
    }
}

// ===========================================================================
extern "C" void kernel_launch(void* const* d_in, const int* in_sizes, int n_in,
                              void* d_out, int out_size, void* d_ws, size_t ws_size,
                              hipStream_t stream) {
    const float* user_emb = (const float*)d_in[0];
    const float* item_emb = (const float*)d_in[1];
    const float* hg_user  = (const float*)d_in[2];
    const float* hg_item  = (const float*)d_in[3];
    const float* adj_vals = (const float*)d_in[4];
    const float* W1       = (const float*)d_in[5];
    const float* b1       = (const float*)d_in[6];
    const float* W2       = (const float*)d_in[7];
    const float* b2       = (const float*)d_in[8];
    const int*   adj_rows = (const int*)d_in[9];
    const int*   adj_cols = (const int*)d_in[10];

    float* out = (float*)d_out;

    // workspace layout
    char* ws = (char*)d_ws;
    size_t off = 0;
    float* h = (float*)(ws + off);        off += (size_t)NUM_NODES * DIM * 4;   // 76.8 MB
    int* cnt    = (int*)(ws + off);       off += (size_t)NUM_NODES * 4;
    int* start  = (int*)(ws + off);       off += (size_t)NUM_NODES * 4;
    int* cursor = (int*)(ws + off);       off += (size_t)NUM_NODES * 4;
    int* part   = (int*)(ws + off);       off += ((size_t)NPART * 4 + 255) & ~255ull;
    int2* packed = (int2*)(ws + off);     off += (size_t)E_EDGES * 8;           // 32 MB
    const size_t need = off;

    const int nodeGrid = (NUM_NODES + 255) / 256;      // 1172
    const int edgeGrid = (E_EDGES + 255) / 256;        // 15625
    const int rowGrid  = (NUM_NODES + 3) / 4;          // 75000 (4 waves/block)

    if (ws_size >= need) {
        // ---- CSR build ----
        zero_counts<<<nodeGrid, 256, 0, stream>>>(cnt);
        hist_rows<<<edgeGrid, 256, 0, stream>>>(adj_rows, cnt);
        scan_blocks<<<NPART, 256, 0, stream>>>(cnt, start, part);
        scan_partials<<<1, 64, 0, stream>>>(part, NPART);
        add_offsets<<<nodeGrid, 256, 0, stream>>>(start, cursor, part);
        scatter_edges<<<edgeGrid, 256, 0, stream>>>(adj_rows, adj_cols, adj_vals,
                                                    cursor, packed);
        // ---- SPMM passes (gather, no float atomics) ----
        spmm_csr<0><<<rowGrid, 256, 0, stream>>>(start, cnt, packed,
                                                 (const float4*)user_emb,
                                                 (const float4*)item_emb,
                                                 (float4*)h, (float4*)out);
        spmm_csr<1><<<rowGrid, 256, 0, stream>>>(start, cnt, packed,
                                                 (const float4*)user_emb,
                                                 (const float4*)item_emb,
                                                 (float4*)h, (float4*)out);
    } else {
        // ---- fallback: R1 atomic path (needs only h) ----
        const int elems4Grid = (NUM_NODES * 16 + 255) / 256;
        const int spmmGrid   = (E_EDGES * 16 + 255) / 256;
        init_ego<<<elems4Grid, 256, 0, stream>>>(
            (const float4*)user_emb, (const float4*)item_emb,
            (float4*)out, (float4*)h);
        spmm_atomic<<<spmmGrid, 256, 0, stream>>>(
            adj_rows, adj_cols, adj_vals, (const float4*)out, h);
        add_inplace<<<elems4Grid, 256, 0, stream>>>((float4*)out, (const float4*)h);
        spmm_atomic<<<spmmGrid, 256, 0, stream>>>(
            adj_rows, adj_cols, adj_vals, (const float4*)h, out);
    }

    // ---- fusion MLP in-place on out ----
    const int fuseBlocks = 2048;
    const int nWavesTotal = fuseBlocks * 4;
    const int nIters = (NUM_NODES + nWavesTotal - 1) / nWavesTotal;
    fuse_kernel<<<fuseBlocks, 256, 0, stream>>>(
        out, hg_user, hg_item, W1, b1, W2, b2, nIters, nWavesTotal);
}

// Round 4
// 1041.218 us; speedup vs baseline: 6.7950x; 1.0554x over previous
//
#include <hip/hip_runtime.h>

#define M_USERS   200000
#define N_ITEMS   100000
#define NUM_NODES 300000   // M + N
#define DIM       64
#define E_EDGES   4000000
#define NPART     ((NUM_NODES + 255) / 256)   // 1172 scan partials
#define NBANDS    8
#define BAND_ROWS (NUM_NODES / NBANDS)        // 37500

__device__ __forceinline__ float lanebc(float x, int k) {
    return __int_as_float(__builtin_amdgcn_readlane(__float_as_int(x), k));
}

// ===========================================================================
// CSR build: histogram -> block scan -> partial scan -> add offsets -> scatter
// ===========================================================================

__global__ void zero_counts(int* __restrict__ cnt) {
    int i = blockIdx.x * blockDim.x + threadIdx.x;
    if (i < NUM_NODES) cnt[i] = 0;
}

__global__ __launch_bounds__(256) void hist_rows(const int* __restrict__ rows,
                                                 int* __restrict__ cnt) {
    int e = blockIdx.x * blockDim.x + threadIdx.x;
    if (e < E_EDGES) atomicAdd(&cnt[rows[e]], 1);
}

__global__ __launch_bounds__(256) void scan_blocks(const int* __restrict__ cnt,
                                                   int* __restrict__ ex,
                                                   int* __restrict__ part) {
    __shared__ int s[256];
    int tid = threadIdx.x;
    int idx = blockIdx.x * 256 + tid;
    int v = (idx < NUM_NODES) ? cnt[idx] : 0;
    s[tid] = v;
    __syncthreads();
    #pragma unroll
    for (int off = 1; off < 256; off <<= 1) {
        int t = (tid >= off) ? s[tid - off] : 0;
        __syncthreads();
        s[tid] += t;
        __syncthreads();
    }
    if (idx < NUM_NODES) ex[idx] = s[tid] - v;
    if (tid == 255) part[blockIdx.x] = s[255];
}

__global__ void scan_partials(int* __restrict__ part, int n) {
    int lane = threadIdx.x;   // blockDim.x == 64
    int carry = 0;
    for (int base = 0; base < n; base += 64) {
        int idx = base + lane;
        int v = (idx < n) ? part[idx] : 0;
        int incl = v;
        #pragma unroll
        for (int off = 1; off < 64; off <<= 1) {
            int t = __shfl_up(incl, off);
            if (lane >= off) incl += t;
        }
        if (idx < n) part[idx] = carry + incl - v;
        carry += __shfl(incl, 63);
    }
}

__global__ void add_offsets(int* __restrict__ start, int* __restrict__ cursor,
                            const int* __restrict__ part) {
    int idx = blockIdx.x * blockDim.x + threadIdx.x;
    if (idx < NUM_NODES) {
        int s = start[idx] + part[idx >> 8];
        start[idx] = s;
        cursor[idx] = s;
    }
}

// banded scatter: only edges whose dest row is in [lo,hi) are written.
// Destination window = 32MB/NBANDS = 4MB -> L2-resident, writes coalesce
// in L2 before one writeback per line.
__global__ __launch_bounds__(256) void scatter_band(const int* __restrict__ rows,
                                                    const int* __restrict__ cols,
                                                    const float* __restrict__ vals,
                                                    int* __restrict__ cursor,
                                                    int2* __restrict__ packed,
                                                    int lo, int hi) {
    int e = blockIdx.x * blockDim.x + threadIdx.x;
    if (e >= E_EDGES) return;
    int r = rows[e];
    if (r >= lo && r < hi) {
        int pos = atomicAdd(&cursor[r], 1);
        packed[pos] = make_int2(cols[e], __float_as_int(vals[e]));
    }
}

// ===========================================================================
// SPMM gather: one wave per row; 16 lanes x float4 per row-read,
// 8 edges in flight per iteration (two 4-edge slots).
// MODE 0: h[r] = sum v * ego[c]                   (ego virtual from user/item)
// MODE 1: out[r] = ego[r] + h[r] + sum v * h[c]   (full acc, undivided)
// ===========================================================================
template <int MODE>
__global__ __launch_bounds__(256) void spmm_csr(
        const int*  __restrict__ start,
        const int*  __restrict__ cnt,
        const int2* __restrict__ packed,
        const float4* __restrict__ user4,
        const float4* __restrict__ item4,
        float4* __restrict__ h4,
        float4* __restrict__ out4) {
    int wave = threadIdx.x >> 6, lane = threadIdx.x & 63;
    int r = blockIdx.x * 4 + wave;
    if (r >= NUM_NODES) return;
    int s = start[r];
    int end = s + cnt[r];
    int sub = lane >> 4;      // edge slot 0..3
    int q   = lane & 15;      // float4 index within the 64-float row

    float4 acc = make_float4(0.f, 0.f, 0.f, 0.f);

    for (int j = s; j < end; j += 8) {
        int iA = j + sub;
        int iB = j + 4 + sub;
        int2 pA = (iA < end) ? packed[iA] : make_int2(0, 0);
        int2 pB = (iB < end) ? packed[iB] : make_int2(0, 0);
        const float4* rowA;
        const float4* rowB;
        if (MODE == 0) {
            rowA = (pA.x < M_USERS) ? user4 + (size_t)pA.x * 16
                                    : item4 + (size_t)(pA.x - M_USERS) * 16;
            rowB = (pB.x < M_USERS) ? user4 + (size_t)pB.x * 16
                                    : item4 + (size_t)(pB.x - M_USERS) * 16;
        } else {
            rowA = h4 + (size_t)pA.x * 16;
            rowB = h4 + (size_t)pB.x * 16;
        }
        float4 xA = rowA[q];
        float4 xB = rowB[q];
        float vA = __int_as_float(pA.y);
        float vB = __int_as_float(pB.y);
        acc.x = fmaf(vA, xA.x, acc.x);
        acc.y = fmaf(vA, xA.y, acc.y);
        acc.z = fmaf(vA, xA.z, acc.z);
        acc.w = fmaf(vA, xA.w, acc.w);
        acc.x = fmaf(vB, xB.x, acc.x);
        acc.y = fmaf(vB, xB.y, acc.y);
        acc.z = fmaf(vB, xB.z, acc.z);
        acc.w = fmaf(vB, xB.w, acc.w);
    }

    acc.x += __shfl_xor(acc.x, 16);
    acc.y += __shfl_xor(acc.y, 16);
    acc.z += __shfl_xor(acc.z, 16);
    acc.w += __shfl_xor(acc.w, 16);
    acc.x += __shfl_xor(acc.x, 32);
    acc.y += __shfl_xor(acc.y, 32);
    acc.z += __shfl_xor(acc.z, 32);
    acc.w += __shfl_xor(acc.w, 32);

    if (lane < 16) {
        size_t o = (size_t)r * 16 + q;
        if (MODE == 0) {
            h4[o] = acc;
        } else {
            float4 ego = (r < M_USERS) ? user4[o]
                                       : item4[(size_t)(r - M_USERS) * 16 + q];
            float4 hh = h4[o];
            float4 res;
            res.x = ego.x + hh.x + acc.x;
            res.y = ego.y + hh.y + acc.y;
            res.z = ego.z + hh.z + acc.z;
            res.w = ego.w + hh.w + acc.w;
            out4[o] = res;
        }
    }
}

// ===========================================================================
// Fallback path (R1): atomic scatter SPMM — used only if ws_size too small
// ===========================================================================
__global__ void init_ego(const float4* __restrict__ user,
                         const float4* __restrict__ item,
                         float4* __restrict__ out,
                         float4* __restrict__ h) {
    int i = blockIdx.x * blockDim.x + threadIdx.x;
    if (i >= NUM_NODES * 16) return;
    float4 v = (i < M_USERS * 16) ? user[i] : item[i - M_USERS * 16];
    out[i] = v;
    h[i] = make_float4(0.f, 0.f, 0.f, 0.f);
}

__global__ __launch_bounds__(256) void spmm_atomic(
        const int*   __restrict__ rows,
        const int*   __restrict__ cols,
        const float* __restrict__ vals,
        const float4* __restrict__ src,
        float*       __restrict__ dst) {
    int t = blockIdx.x * blockDim.x + threadIdx.x;
    if (t >= E_EDGES * 16) return;
    int e = t >> 4;
    int part = t & 15;
    int r = rows[e];
    int c = cols[e];
    float v = vals[e];
    float4 x = src[c * 16 + part];
    float* d = dst + (size_t)r * DIM + part * 4;
    atomicAdd(d + 0, x.x * v);
    atomicAdd(d + 1, x.y * v);
    atomicAdd(d + 2, x.z * v);
    atomicAdd(d + 3, x.w * v);
}

__global__ void add_inplace(float4* __restrict__ out, const float4* __restrict__ h) {
    int i = blockIdx.x * blockDim.x + threadIdx.x;
    if (i >= NUM_NODES * 16) return;
    float4 a = out[i], b = h[i];
    a.x += b.x; a.y += b.y; a.z += b.z; a.w += b.w;
    out[i] = a;
}

// ===========================================================================
// Fusion MLP: 4 rows per wave, f1/f2 in registers, cat[k] via v_readlane,
// W1 LDS read amortized over 4 rows. No per-iter __syncthreads.
// ===========================================================================
__global__ __launch_bounds__(256) void fuse_kernel(
        float* __restrict__ acc,            // d_out: acc in, fused out
        const float* __restrict__ hg_user,
        const float* __restrict__ hg_item,
        const float* __restrict__ W1,       // (128, 64) row-major
        const float* __restrict__ b1,       // (64)
        const float* __restrict__ W2,       // (64, 2) row-major
        const float* __restrict__ b2,       // (2)
        int nIters, int nWavesTotal) {
    __shared__ float W1s[128 * 64];
    __shared__ float W2s[128];
    __shared__ float b1s[64];

    int tid = threadIdx.x;
    for (int i = tid; i < 128 * 64; i += 256) W1s[i] = W1[i];
    if (tid < 128) W2s[tid] = W2[tid];
    if (tid < 64)  b1s[tid] = b1[tid];
    __syncthreads();
    float b2_0 = b2[0], b2_1 = b2[1];

    int wave = tid >> 6, lane = tid & 63;
    int gwave = blockIdx.x * 4 + wave;

    for (int it = 0; it < nIters; ++it) {
        int quad = gwave + it * nWavesTotal;   // wave-uniform
        int r0 = quad * 4;
        if (r0 >= NUM_NODES) break;            // NUM_NODES % 4 == 0: whole quad valid

        float f1[4], f2[4], h[4];
        #pragma unroll
        for (int i = 0; i < 4; ++i) {
            int r = r0 + i;
            f1[i] = acc[(size_t)r * DIM + lane] * (1.0f / 3.0f);
            f2[i] = (r < M_USERS)
                    ? hg_user[(size_t)r * DIM + lane]
                    : hg_item[(size_t)(r - M_USERS) * DIM + lane];
            h[i] = b1s[lane];
        }
        #pragma unroll
        for (int k = 0; k < 64; ++k) {
            float w1k = W1s[k * 64 + lane];
            #pragma unroll
            for (int i = 0; i < 4; ++i)
                h[i] = fmaf(lanebc(f1[i], k), w1k, h[i]);
        }
        #pragma unroll
        for (int k = 0; k < 64; ++k) {
            float w1k = W1s[(64 + k) * 64 + lane];
            #pragma unroll
            for (int i = 0; i < 4; ++i)
                h[i] = fmaf(lanebc(f2[i], k), w1k, h[i]);
        }
        #pragma unroll
        for (int i = 0; i < 4; ++i) {
            float hh = tanhf(h[i]);
            float p0 = hh * W2s[lane * 2 + 0];
            float p1 = hh * W2s[lane * 2 + 1];
            #pragma unroll
            for (int off = 32; off; off >>= 1) {
                p0 += __shfl_xor(p0, off);
                p1 += __shfl_xor(p1, off);
            }
            float w0 = 1.0f / (1.0f + __expf((p1 + b2_1) - (p0 + b2_0)));
            acc[(size_t)(r0 + i) * DIM + lane] = w0 * f1[i] + (1.0f - w0) * f2[i];
        }
    }
}

// ===========================================================================
extern "C" void kernel_launch(void* const* d_in, const int* in_sizes, int n_in,
                              void* d_out, int out_size, void* d_ws, size_t ws_size,
                              hipStream_t stream) {
    const float* user_emb = (const float*)d_in[0];
    const float* item_emb = (const float*)d_in[1];
    const float* hg_user  = (const float*)d_in[2];
    const float* hg_item  = (const float*)d_in[3];
    const float* adj_vals = (const float*)d_in[4];
    const float* W1       = (const float*)d_in[5];
    const float* b1       = (const float*)d_in[6];
    const float* W2       = (const float*)d_in[7];
    const float* b2       = (const float*)d_in[8];
    const int*   adj_rows = (const int*)d_in[9];
    const int*   adj_cols = (const int*)d_in[10];

    float* out = (float*)d_out;

    // workspace layout
    char* ws = (char*)d_ws;
    size_t off = 0;
    float* h = (float*)(ws + off);        off += (size_t)NUM_NODES * DIM * 4;   // 76.8 MB
    int* cnt    = (int*)(ws + off);       off += (size_t)NUM_NODES * 4;
    int* start  = (int*)(ws + off);       off += (size_t)NUM_NODES * 4;
    int* cursor = (int*)(ws + off);       off += (size_t)NUM_NODES * 4;
    int* part   = (int*)(ws + off);       off += ((size_t)NPART * 4 + 255) & ~255ull;
    int2* packed = (int2*)(ws + off);     off += (size_t)E_EDGES * 8;           // 32 MB
    const size_t need = off;

    const int nodeGrid = (NUM_NODES + 255) / 256;      // 1172
    const int edgeGrid = (E_EDGES + 255) / 256;        // 15625
    const int rowGrid  = (NUM_NODES + 3) / 4;          // 75000 (4 waves/block)

    if (ws_size >= need) {
        // ---- CSR build ----
        zero_counts<<<nodeGrid, 256, 0, stream>>>(cnt);
        hist_rows<<<edgeGrid, 256, 0, stream>>>(adj_rows, cnt);
        scan_blocks<<<NPART, 256, 0, stream>>>(cnt, start, part);
        scan_partials<<<1, 64, 0, stream>>>(part, NPART);
        add_offsets<<<nodeGrid, 256, 0, stream>>>(start, cursor, part);
        for (int b = 0; b < NBANDS; ++b) {
            scatter_band<<<edgeGrid, 256, 0, stream>>>(
                adj_rows, adj_cols, adj_vals, cursor, packed,
                b * BAND_ROWS, (b + 1) * BAND_ROWS);
        }
        // ---- SPMM passes (gather, no float atomics) ----
        spmm_csr<0><<<rowGrid, 256, 0, stream>>>(start, cnt, packed,
                                                 (const float4*)user_emb,
                                                 (const float4*)item_emb,
                                                 (float4*)h, (float4*)out);
        spmm_csr<1><<<rowGrid, 256, 0, stream>>>(start, cnt, packed,
                                                 (const float4*)user_emb,
                                                 (const float4*)item_emb,
                                                 (float4*)h, (float4*)out);
    } else {
        // ---- fallback: R1 atomic path (needs only h) ----
        const int elems4Grid = (NUM_NODES * 16 + 255) / 256;
        const int spmmGrid   = (E_EDGES * 16 + 255) / 256;
        init_ego<<<elems4Grid, 256, 0, stream>>>(
            (const float4*)user_emb, (const float4*)item_emb,
            (float4*)out, (float4*)h);
        spmm_atomic<<<spmmGrid, 256, 0, stream>>>(
            adj_rows, adj_cols, adj_vals, (const float4*)out, h);
        add_inplace<<<elems4Grid, 256, 0, stream>>>((float4*)out, (const float4*)h);
        spmm_atomic<<<spmmGrid, 256, 0, stream>>>(
            adj_rows, adj_cols, adj_vals, (const float4*)h, out);
    }

    // ---- fusion MLP in-place on out ----
    const int fuseBlocks = 2048;
    const int nWavesTotal = fuseBlocks * 4;
    const int nQuads = NUM_NODES / 4;                          // 75000
    const int nIters = (nQuads + nWavesTotal - 1) / nWavesTotal;
    fuse_kernel<<<fuseBlocks, 256, 0, stream>>>(
        out, hg_user, hg_item, W1, b1, W2, b2, nIters, nWavesTotal);
}

// Round 5
// 808.370 us; speedup vs baseline: 8.7522x; 1.2880x over previous
//
#include <hip/hip_runtime.h>
#include <hip/hip_bf16.h>

#define M_USERS   200000
#define N_ITEMS   100000
#define NUM_NODES 300000   // M + N
#define DIM       64
#define E_EDGES   4000000
#define NPART     ((NUM_NODES + 255) / 256)   // 1172 scan partials
#define NBANDS    8
#define BAND_ROWS (NUM_NODES / NBANDS)        // 37500
#define NGROUPS   (NUM_NODES / 16)            // 18750 row-groups of 16
#define GPW       4                           // groups per wave in fuse

typedef __attribute__((ext_vector_type(8))) short bf16x8;   // 8 bf16 (4 VGPRs)
typedef __attribute__((ext_vector_type(4))) float f32x4;    // 4 fp32

__device__ __forceinline__ short f2bf(float x) {
    __hip_bfloat16 h = __float2bfloat16(x);
    return *reinterpret_cast<short*>(&h);
}

// ===========================================================================
// CSR build: histogram -> block scan -> partial scan -> add offsets -> scatter
// ===========================================================================

__global__ void zero_counts(int* __restrict__ cnt) {
    int i = blockIdx.x * blockDim.x + threadIdx.x;
    if (i < NUM_NODES) cnt[i] = 0;
}

__global__ __launch_bounds__(256) void hist_rows(const int* __restrict__ rows,
                                                 int* __restrict__ cnt) {
    int e = blockIdx.x * blockDim.x + threadIdx.x;
    if (e < E_EDGES) atomicAdd(&cnt[rows[e]], 1);
}

__global__ __launch_bounds__(256) void scan_blocks(const int* __restrict__ cnt,
                                                   int* __restrict__ ex,
                                                   int* __restrict__ part) {
    __shared__ int s[256];
    int tid = threadIdx.x;
    int idx = blockIdx.x * 256 + tid;
    int v = (idx < NUM_NODES) ? cnt[idx] : 0;
    s[tid] = v;
    __syncthreads();
    #pragma unroll
    for (int off = 1; off < 256; off <<= 1) {
        int t = (tid >= off) ? s[tid - off] : 0;
        __syncthreads();
        s[tid] += t;
        __syncthreads();
    }
    if (idx < NUM_NODES) ex[idx] = s[tid] - v;
    if (tid == 255) part[blockIdx.x] = s[255];
}

__global__ void scan_partials(int* __restrict__ part, int n) {
    int lane = threadIdx.x;   // blockDim.x == 64
    int carry = 0;
    for (int base = 0; base < n; base += 64) {
        int idx = base + lane;
        int v = (idx < n) ? part[idx] : 0;
        int incl = v;
        #pragma unroll
        for (int off = 1; off < 64; off <<= 1) {
            int t = __shfl_up(incl, off);
            if (lane >= off) incl += t;
        }
        if (idx < n) part[idx] = carry + incl - v;
        carry += __shfl(incl, 63);
    }
}

__global__ void add_offsets(int* __restrict__ start, int* __restrict__ cursor,
                            const int* __restrict__ part) {
    int idx = blockIdx.x * blockDim.x + threadIdx.x;
    if (idx < NUM_NODES) {
        int s = start[idx] + part[idx >> 8];
        start[idx] = s;
        cursor[idx] = s;
    }
}

// banded scatter: only edges whose dest row is in [lo,hi) are written.
// Destination window = 4MB -> L2-resident, writes coalesce before writeback.
__global__ __launch_bounds__(256) void scatter_band(const int* __restrict__ rows,
                                                    const int* __restrict__ cols,
                                                    const float* __restrict__ vals,
                                                    int* __restrict__ cursor,
                                                    int2* __restrict__ packed,
                                                    int lo, int hi) {
    int e = blockIdx.x * blockDim.x + threadIdx.x;
    if (e >= E_EDGES) return;
    int r = rows[e];
    if (r >= lo && r < hi) {
        int pos = atomicAdd(&cursor[r], 1);
        packed[pos] = make_int2(cols[e], __float_as_int(vals[e]));
    }
}

// ===========================================================================
// SPMM gather: one wave per row; 16 lanes x float4 per row-read,
// 8 edges in flight per iteration (two 4-edge slots).
// MODE 0: h[r] = sum v * ego[c]                   (ego virtual from user/item)
// MODE 1: out[r] = ego[r] + h[r] + sum v * h[c]   (full acc, undivided)
// ===========================================================================
template <int MODE>
__global__ __launch_bounds__(256) void spmm_csr(
        const int*  __restrict__ start,
        const int*  __restrict__ cnt,
        const int2* __restrict__ packed,
        const float4* __restrict__ user4,
        const float4* __restrict__ item4,
        float4* __restrict__ h4,
        float4* __restrict__ out4) {
    int wave = threadIdx.x >> 6, lane = threadIdx.x & 63;
    int r = blockIdx.x * 4 + wave;
    if (r >= NUM_NODES) return;
    int s = start[r];
    int end = s + cnt[r];
    int sub = lane >> 4;      // edge slot 0..3
    int q   = lane & 15;      // float4 index within the 64-float row

    float4 acc = make_float4(0.f, 0.f, 0.f, 0.f);

    for (int j = s; j < end; j += 8) {
        int iA = j + sub;
        int iB = j + 4 + sub;
        int2 pA = (iA < end) ? packed[iA] : make_int2(0, 0);
        int2 pB = (iB < end) ? packed[iB] : make_int2(0, 0);
        const float4* rowA;
        const float4* rowB;
        if (MODE == 0) {
            rowA = (pA.x < M_USERS) ? user4 + (size_t)pA.x * 16
                                    : item4 + (size_t)(pA.x - M_USERS) * 16;
            rowB = (pB.x < M_USERS) ? user4 + (size_t)pB.x * 16
                                    : item4 + (size_t)(pB.x - M_USERS) * 16;
        } else {
            rowA = h4 + (size_t)pA.x * 16;
            rowB = h4 + (size_t)pB.x * 16;
        }
        float4 xA = rowA[q];
        float4 xB = rowB[q];
        float vA = __int_as_float(pA.y);
        float vB = __int_as_float(pB.y);
        acc.x = fmaf(vA, xA.x, acc.x);
        acc.y = fmaf(vA, xA.y, acc.y);
        acc.z = fmaf(vA, xA.z, acc.z);
        acc.w = fmaf(vA, xA.w, acc.w);
        acc.x = fmaf(vB, xB.x, acc.x);
        acc.y = fmaf(vB, xB.y, acc.y);
        acc.z = fmaf(vB, xB.z, acc.z);
        acc.w = fmaf(vB, xB.w, acc.w);
    }

    acc.x += __shfl_xor(acc.x, 16);
    acc.y += __shfl_xor(acc.y, 16);
    acc.z += __shfl_xor(acc.z, 16);
    acc.w += __shfl_xor(acc.w, 16);
    acc.x += __shfl_xor(acc.x, 32);
    acc.y += __shfl_xor(acc.y, 32);
    acc.z += __shfl_xor(acc.z, 32);
    acc.w += __shfl_xor(acc.w, 32);

    if (lane < 16) {
        size_t o = (size_t)r * 16 + q;
        if (MODE == 0) {
            h4[o] = acc;
        } else {
            float4 ego = (r < M_USERS) ? user4[o]
                                       : item4[(size_t)(r - M_USERS) * 16 + q];
            float4 hh = h4[o];
            float4 res;
            res.x = ego.x + hh.x + acc.x;
            res.y = ego.y + hh.y + acc.y;
            res.z = ego.z + hh.z + acc.z;
            res.w = ego.w + hh.w + acc.w;
            out4[o] = res;
        }
    }
}

// ===========================================================================
// Fallback path (R1): atomic scatter SPMM — used only if ws_size too small
// ===========================================================================
__global__ void init_ego(const float4* __restrict__ user,
                         const float4* __restrict__ item,
                         float4* __restrict__ out,
                         float4* __restrict__ h) {
    int i = blockIdx.x * blockDim.x + threadIdx.x;
    if (i >= NUM_NODES * 16) return;
    float4 v = (i < M_USERS * 16) ? user[i] : item[i - M_USERS * 16];
    out[i] = v;
    h[i] = make_float4(0.f, 0.f, 0.f, 0.f);
}

__global__ __launch_bounds__(256) void spmm_atomic(
        const int*   __restrict__ rows,
        const int*   __restrict__ cols,
        const float* __restrict__ vals,
        const float4* __restrict__ src,
        float*       __restrict__ dst) {
    int t = blockIdx.x * blockDim.x + threadIdx.x;
    if (t >= E_EDGES * 16) return;
    int e = t >> 4;
    int part = t & 15;
    int r = rows[e];
    int c = cols[e];
    float v = vals[e];
    float4 x = src[c * 16 + part];
    float* d = dst + (size_t)r * DIM + part * 4;
    atomicAdd(d + 0, x.x * v);
    atomicAdd(d + 1, x.y * v);
    atomicAdd(d + 2, x.z * v);
    atomicAdd(d + 3, x.w * v);
}

__global__ void add_inplace(float4* __restrict__ out, const float4* __restrict__ h) {
    int i = blockIdx.x * blockDim.x + threadIdx.x;
    if (i >= NUM_NODES * 16) return;
    float4 a = out[i], b = h[i];
    a.x += b.x; a.y += b.y; a.z += b.z; a.w += b.w;
    out[i] = a;
}

// ===========================================================================
// Fusion MLP via MFMA: one wave per 16-row group (GPW groups per wave).
// H[16x64] = cat[16x128] @ W1[128x64] + b1, via mfma_f32_16x16x32_bf16:
//   A-frag: lane l holds cat[l&15][32*kk + (l>>4)*8 + j], j=0..7 (bf16)
//   B-frag: lane l holds W1 [32*kk + (l>>4)*8 + j][16*t + (l&15)]  (bf16, regs)
//   C/D   : lane l holds H  [(l>>4)*4 + q][16*t + (l&15)]          (m89 layout)
// f1(=acc/3)/f2 stay fp32 in registers for the final blend. No LDS.
// ===========================================================================
__global__ __launch_bounds__(256) void fuse_mfma(
        float* __restrict__ acc,            // d_out: acc in, fused out
        const float* __restrict__ hg_user,
        const float* __restrict__ hg_item,
        const float* __restrict__ W1,       // (128, 64) row-major
        const float* __restrict__ b1,       // (64)
        const float* __restrict__ W2,       // (64, 2) row-major
        const float* __restrict__ b2,       // (2)
        int nGroups) {
    int tid  = threadIdx.x;
    int lane = tid & 63;
    int gid  = blockIdx.x * 4 + (tid >> 6);
    int lr   = lane & 15;     // A-row / B,C-col within tile
    int lg   = lane >> 4;     // k sub-group

    // ---- B fragments (W1 bf16), loaded once per wave; W1 is L2-resident ----
    bf16x8 bfrag[16];
    #pragma unroll
    for (int kk = 0; kk < 4; ++kk)
        #pragma unroll
        for (int t = 0; t < 4; ++t)
            #pragma unroll
            for (int j = 0; j < 8; ++j)
                bfrag[kk * 4 + t][j] =
                    f2bf(W1[(kk * 32 + lg * 8 + j) * 64 + t * 16 + lr]);

    float b1v[4], w2a[4], w2b[4];
    #pragma unroll
    for (int t = 0; t < 4; ++t) {
        int c = t * 16 + lr;
        b1v[t] = b1[c];
        w2a[t] = W2[c * 2 + 0];
        w2b[t] = W2[c * 2 + 1];
    }
    float b2_0 = b2[0], b2_1 = b2[1];
    int srcLane = (lr >> 2) << 4;   // lane holding w0 for row lr (at q = lr&3)
    int sel = lr & 3;

    for (int g2 = 0; g2 < GPW; ++g2) {
        int grp = gid * GPW + g2;
        if (grp >= nGroups) break;
        int r = grp * 16 + lr;                       // this lane's row
        const float* f1p = acc + (size_t)r * DIM;
        const float* f2p = (r < M_USERS)
                           ? hg_user + (size_t)r * DIM
                           : hg_item + (size_t)(r - M_USERS) * DIM;

        // ---- load A data (8 fp32 per kk slice), keep fp32 for the blend ----
        float fr[4][8];
        #pragma unroll
        for (int kk = 0; kk < 4; ++kk) {
            const float* sp = (kk < 2) ? f1p : f2p;
            int cb = (kk & 1) * 32 + lg * 8;
            float4 u0 = *(const float4*)(sp + cb);
            float4 u1 = *(const float4*)(sp + cb + 4);
            float s = (kk < 2) ? (1.0f / 3.0f) : 1.0f;
            fr[kk][0] = u0.x * s; fr[kk][1] = u0.y * s;
            fr[kk][2] = u0.z * s; fr[kk][3] = u0.w * s;
            fr[kk][4] = u1.x * s; fr[kk][5] = u1.y * s;
            fr[kk][6] = u1.z * s; fr[kk][7] = u1.w * s;
        }

        // ---- MFMA: 4 K-slices x 4 col-tiles ----
        f32x4 ct[4];
        #pragma unroll
        for (int t = 0; t < 4; ++t) ct[t] = (f32x4){0.f, 0.f, 0.f, 0.f};
        #pragma unroll
        for (int kk = 0; kk < 4; ++kk) {
            bf16x8 af;
            #pragma unroll
            for (int j = 0; j < 8; ++j) af[j] = f2bf(fr[kk][j]);
            #pragma unroll
            for (int t = 0; t < 4; ++t)
                ct[t] = __builtin_amdgcn_mfma_f32_16x16x32_bf16(
                            af, bfrag[kk * 4 + t], ct[t], 0, 0, 0);
        }

        // ---- tanh + logits (per lane: rows lg*4+q, col t*16+lr) ----
        float p0[4] = {0.f, 0.f, 0.f, 0.f};
        float p1[4] = {0.f, 0.f, 0.f, 0.f};
        #pragma unroll
        for (int t = 0; t < 4; ++t)
            #pragma unroll
            for (int q = 0; q < 4; ++q) {
                float hh = tanhf(ct[t][q] + b1v[t]);
                p0[q] = fmaf(hh, w2a[t], p0[q]);
                p1[q] = fmaf(hh, w2b[t], p1[q]);
            }
        #pragma unroll
        for (int q = 0; q < 4; ++q) {
            #pragma unroll
            for (int off = 1; off < 16; off <<= 1) {
                p0[q] += __shfl_xor(p0[q], off);
                p1[q] += __shfl_xor(p1[q], off);
            }
        }
        float w0q[4];
        #pragma unroll
        for (int q = 0; q < 4; ++q)
            w0q[q] = 1.0f / (1.0f + __expf((p1[q] + b2_1) - (p0[q] + b2_0)));

        // broadcast w0 of row lr to lane: held by group lr>>2 at index lr&3
        float bq0 = __shfl(w0q[0], srcLane);
        float bq1 = __shfl(w0q[1], srcLane);
        float bq2 = __shfl(w0q[2], srcLane);
        float bq3 = __shfl(w0q[3], srcLane);
        float w0f = (sel == 0) ? bq0 : (sel == 1) ? bq1 : (sel == 2) ? bq2 : bq3;
        float w1f = 1.0f - w0f;

        // ---- blend + store: fr[0/1] = f1 halves, fr[2/3] = f2 halves ----
        float* outp = acc + (size_t)r * DIM;
        #pragma unroll
        for (int half = 0; half < 2; ++half) {
            int cb = half * 32 + lg * 8;
            float4 o0, o1;
            o0.x = w0f * fr[half][0] + w1f * fr[half + 2][0];
            o0.y = w0f * fr[half][1] + w1f * fr[half + 2][1];
            o0.z = w0f * fr[half][2] + w1f * fr[half + 2][2];
            o0.w = w0f * fr[half][3] + w1f * fr[half + 2][3];
            o1.x = w0f * fr[half][4] + w1f * fr[half + 2][4];
            o1.y = w0f * fr[half][5] + w1f * fr[half + 2][5];
            o1.z = w0f * fr[half][6] + w1f * fr[half + 2][6];
            o1.w = w0f * fr[half][7] + w1f * fr[half + 2][7];
            *(float4*)(outp + cb)     = o0;
            *(float4*)(outp + cb + 4) = o1;
        }
    }
}

// ===========================================================================
extern "C" void kernel_launch(void* const* d_in, const int* in_sizes, int n_in,
                              void* d_out, int out_size, void* d_ws, size_t ws_size,
                              hipStream_t stream) {
    const float* user_emb = (const float*)d_in[0];
    const float* item_emb = (const float*)d_in[1];
    const float* hg_user  = (const float*)d_in[2];
    const float* hg_item  = (const float*)d_in[3];
    const float* adj_vals = (const float*)d_in[4];
    const float* W1       = (const float*)d_in[5];
    const float* b1       = (const float*)d_in[6];
    const float* W2       = (const float*)d_in[7];
    const float* b2       = (const float*)d_in[8];
    const int*   adj_rows = (const int*)d_in[9];
    const int*   adj_cols = (const int*)d_in[10];

    float* out = (float*)d_out;

    // workspace layout
    char* ws = (char*)d_ws;
    size_t off = 0;
    float* h = (float*)(ws + off);        off += (size_t)NUM_NODES * DIM * 4;   // 76.8 MB
    int* cnt    = (int*)(ws + off);       off += (size_t)NUM_NODES * 4;
    int* start  = (int*)(ws + off);       off += (size_t)NUM_NODES * 4;
    int* cursor = (int*)(ws + off);       off += (size_t)NUM_NODES * 4;
    int* part   = (int*)(ws + off);       off += ((size_t)NPART * 4 + 255) & ~255ull;
    int2* packed = (int2*)(ws + off);     off += (size_t)E_EDGES * 8;           // 32 MB
    const size_t need = off;

    const int nodeGrid = (NUM_NODES + 255) / 256;      // 1172
    const int edgeGrid = (E_EDGES + 255) / 256;        // 15625
    const int rowGrid  = (NUM_NODES + 3) / 4;          // 75000 (4 waves/block)

    if (ws_size >= need) {
        // ---- CSR build ----
        zero_counts<<<nodeGrid, 256, 0, stream>>>(cnt);
        hist_rows<<<edgeGrid, 256, 0, stream>>>(adj_rows, cnt);
        scan_blocks<<<NPART, 256, 0, stream>>>(cnt, start, part);
        scan_partials<<<1, 64, 0, stream>>>(part, NPART);
        add_offsets<<<nodeGrid, 256, 0, stream>>>(start, cursor, part);
        for (int b = 0; b < NBANDS; ++b) {
            scatter_band<<<edgeGrid, 256, 0, stream>>>(
                adj_rows, adj_cols, adj_vals, cursor, packed,
                b * BAND_ROWS, (b + 1) * BAND_ROWS);
        }
        // ---- SPMM passes (gather, no float atomics) ----
        spmm_csr<0><<<rowGrid, 256, 0, stream>>>(start, cnt, packed,
                                                 (const float4*)user_emb,
                                                 (const float4*)item_emb,
                                                 (float4*)h, (float4*)out);
        spmm_csr<1><<<rowGrid, 256, 0, stream>>>(start, cnt, packed,
                                                 (const float4*)user_emb,
                                                 (const float4*)item_emb,
                                                 (float4*)h, (float4*)out);
    } else {
        // ---- fallback: R1 atomic path (needs only h) ----
        const int elems4Grid = (NUM_NODES * 16 + 255) / 256;
        const int spmmGrid   = (E_EDGES * 16 + 255) / 256;
        init_ego<<<elems4Grid, 256, 0, stream>>>(
            (const float4*)user_emb, (const float4*)item_emb,
            (float4*)out, (float4*)h);
        spmm_atomic<<<spmmGrid, 256, 0, stream>>>(
            adj_rows, adj_cols, adj_vals, (const float4*)out, h);
        add_inplace<<<elems4Grid, 256, 0, stream>>>((float4*)out, (const float4*)h);
        spmm_atomic<<<spmmGrid, 256, 0, stream>>>(
            adj_rows, adj_cols, adj_vals, (const float4*)h, out);
    }

    // ---- fusion MLP in-place on out (MFMA) ----
    const int fuseWaves  = (NGROUPS + GPW - 1) / GPW;          // 4688
    const int fuseBlocks = (fuseWaves + 3) / 4;                // 1172
    fuse_mfma<<<fuseBlocks, 256, 0, stream>>>(
        out, hg_user, hg_item, W1, b1, W2, b2, NGROUPS);
}

// Round 6
// 726.155 us; speedup vs baseline: 9.7432x; 1.1132x over previous
//
#include <hip/hip_runtime.h>
#include <hip/hip_bf16.h>

#define M_USERS   200000
#define N_ITEMS   100000
#define NUM_NODES 300000   // M + N
#define DIM       64
#define E_EDGES   4000000
#define NPART     ((NUM_NODES + 255) / 256)   // 1172 scan partials
#define NBANDS    8
#define BAND_ROWS (NUM_NODES / NBANDS)        // 37500
#define NGROUPS   (NUM_NODES / 16)            // 18750 row-groups of 16
#define GPW       4                           // groups per wave in fuse

typedef __attribute__((ext_vector_type(8))) short bf16x8;   // 8 bf16 (4 VGPRs)
typedef __attribute__((ext_vector_type(4))) float f32x4;    // 4 fp32

__device__ __forceinline__ short f2bf(float x) {
    __hip_bfloat16 h = __float2bfloat16(x);
    return *reinterpret_cast<short*>(&h);
}

// bf16 pair pack/unpack (RN-even rounding on pack)
__device__ __forceinline__ unsigned bfpack(float a, float b) {
    unsigned ua = __float_as_uint(a), ub = __float_as_uint(b);
    unsigned ra = (ua + 0x7fffu + ((ua >> 16) & 1u)) >> 16;
    unsigned rb = (ub + 0x7fffu + ((ub >> 16) & 1u)) >> 16;
    return ra | (rb << 16);
}
__device__ __forceinline__ float bflo(unsigned u) { return __uint_as_float(u << 16); }
__device__ __forceinline__ float bfhi(unsigned u) { return __uint_as_float(u & 0xffff0000u); }

// ===========================================================================
// CSR build: histogram(+bandId) -> scan -> offsets -> banded scatter
// ===========================================================================

__global__ void zero_counts(int* __restrict__ cnt) {
    int i = blockIdx.x * blockDim.x + threadIdx.x;
    if (i < NUM_NODES) cnt[i] = 0;
}

// histogram + emit 1-byte band id per edge (prefilter for scatter passes)
__global__ __launch_bounds__(256) void hist_rows_band(const int* __restrict__ rows,
                                                      int* __restrict__ cnt,
                                                      unsigned char* __restrict__ bandId) {
    int e = blockIdx.x * blockDim.x + threadIdx.x;
    if (e < E_EDGES) {
        int r = rows[e];
        atomicAdd(&cnt[r], 1);
        if (bandId) bandId[e] = (unsigned char)(r / BAND_ROWS);
    }
}

__global__ __launch_bounds__(256) void scan_blocks(const int* __restrict__ cnt,
                                                   int* __restrict__ ex,
                                                   int* __restrict__ part) {
    __shared__ int s[256];
    int tid = threadIdx.x;
    int idx = blockIdx.x * 256 + tid;
    int v = (idx < NUM_NODES) ? cnt[idx] : 0;
    s[tid] = v;
    __syncthreads();
    #pragma unroll
    for (int off = 1; off < 256; off <<= 1) {
        int t = (tid >= off) ? s[tid - off] : 0;
        __syncthreads();
        s[tid] += t;
        __syncthreads();
    }
    if (idx < NUM_NODES) ex[idx] = s[tid] - v;
    if (tid == 255) part[blockIdx.x] = s[255];
}

__global__ void scan_partials(int* __restrict__ part, int n) {
    int lane = threadIdx.x;   // blockDim.x == 64
    int carry = 0;
    for (int base = 0; base < n; base += 64) {
        int idx = base + lane;
        int v = (idx < n) ? part[idx] : 0;
        int incl = v;
        #pragma unroll
        for (int off = 1; off < 64; off <<= 1) {
            int t = __shfl_up(incl, off);
            if (lane >= off) incl += t;
        }
        if (idx < n) part[idx] = carry + incl - v;
        carry += __shfl(incl, 63);
    }
}

__global__ void add_offsets(int* __restrict__ start, int* __restrict__ cursor,
                            const int* __restrict__ part) {
    int idx = blockIdx.x * blockDim.x + threadIdx.x;
    if (idx < NUM_NODES) {
        int s = start[idx] + part[idx >> 8];
        start[idx] = s;
        cursor[idx] = s;
    }
}

// banded scatter with bandId prefilter: reads 4MB of ids/pass instead of 16MB rows
__global__ __launch_bounds__(256) void scatter_band_pref(
        const int* __restrict__ rows,
        const int* __restrict__ cols,
        const float* __restrict__ vals,
        const unsigned char* __restrict__ bandId,
        int* __restrict__ cursor,
        int2* __restrict__ packed,
        int band) {
    int e = blockIdx.x * blockDim.x + threadIdx.x;
    if (e >= E_EDGES) return;
    if (bandId[e] == (unsigned char)band) {
        int r = rows[e];
        int pos = atomicAdd(&cursor[r], 1);
        packed[pos] = make_int2(cols[e], __float_as_int(vals[e]));
    }
}

// banded scatter without prefilter (Tier-2)
__global__ __launch_bounds__(256) void scatter_band(const int* __restrict__ rows,
                                                    const int* __restrict__ cols,
                                                    const float* __restrict__ vals,
                                                    int* __restrict__ cursor,
                                                    int2* __restrict__ packed,
                                                    int lo, int hi) {
    int e = blockIdx.x * blockDim.x + threadIdx.x;
    if (e >= E_EDGES) return;
    int r = rows[e];
    if (r >= lo && r < hi) {
        int pos = atomicAdd(&cursor[r], 1);
        packed[pos] = make_int2(cols[e], __float_as_int(vals[e]));
    }
}

// ===========================================================================
// bf16 ego table build: 8 floats -> 8 bf16 (16B) per thread
// ===========================================================================
__global__ __launch_bounds__(256) void make_egobf(const float4* __restrict__ user,
                                                  const float4* __restrict__ item,
                                                  uint4* __restrict__ ego) {
    int c = blockIdx.x * blockDim.x + threadIdx.x;   // chunk of 8 floats
    if (c >= NUM_NODES * 8) return;
    const float4* src = (c < M_USERS * 8) ? user + (size_t)c * 2
                                          : item + ((size_t)c - M_USERS * 8) * 2;
    float4 u0 = src[0], u1 = src[1];
    uint4 w;
    w.x = bfpack(u0.x, u0.y);
    w.y = bfpack(u0.z, u0.w);
    w.z = bfpack(u1.x, u1.y);
    w.w = bfpack(u1.z, u1.w);
    ego[c] = w;
}

// ===========================================================================
// SPMM gather over bf16 tables: one wave per row; 8 edge slots x 8 lanes,
// each lane reads 16B (8 bf16) -> 16 edges in flight per iteration.
// MODE 0: hbf[r] = bf16( sum v * egobf[c] )
// MODE 1: out[r] = ego_fp32[r] + hbf[r] + sum v * hbf[c]   (fp32 out)
// ===========================================================================
template <int MODE>
__global__ __launch_bounds__(256) void spmm_bf(
        const int*  __restrict__ start,
        const int*  __restrict__ endp,     // cursor after scatter = start+cnt
        const int2* __restrict__ packed,
        const uint4* __restrict__ src,     // bf16 table: 8 uint4 per row
        uint4* __restrict__ hbf,           // MODE 0 dest
        const float4* __restrict__ user4,  // MODE 1: fp32 ego
        const float4* __restrict__ item4,
        float4* __restrict__ out4) {
    int wave = threadIdx.x >> 6, lane = threadIdx.x & 63;
    int r = blockIdx.x * 4 + wave;
    if (r >= NUM_NODES) return;
    int s = start[r];
    int end = endp[r];
    int sub = lane >> 3;      // edge slot 0..7
    int q   = lane & 7;       // uint4 (8 bf16) index within the 128B row

    float acc[8] = {0.f, 0.f, 0.f, 0.f, 0.f, 0.f, 0.f, 0.f};

    for (int j = s; j < end; j += 16) {
        int iA = j + sub;
        int iB = j + 8 + sub;
        int2 pA = (iA < end) ? packed[iA] : make_int2(0, 0);
        int2 pB = (iB < end) ? packed[iB] : make_int2(0, 0);
        uint4 xA = src[(size_t)pA.x * 8 + q];
        uint4 xB = src[(size_t)pB.x * 8 + q];
        float vA = __int_as_float(pA.y);
        float vB = __int_as_float(pB.y);
        acc[0] = fmaf(vA, bflo(xA.x), acc[0]);
        acc[1] = fmaf(vA, bfhi(xA.x), acc[1]);
        acc[2] = fmaf(vA, bflo(xA.y), acc[2]);
        acc[3] = fmaf(vA, bfhi(xA.y), acc[3]);
        acc[4] = fmaf(vA, bflo(xA.z), acc[4]);
        acc[5] = fmaf(vA, bfhi(xA.z), acc[5]);
        acc[6] = fmaf(vA, bflo(xA.w), acc[6]);
        acc[7] = fmaf(vA, bfhi(xA.w), acc[7]);
        acc[0] = fmaf(vB, bflo(xB.x), acc[0]);
        acc[1] = fmaf(vB, bfhi(xB.x), acc[1]);
        acc[2] = fmaf(vB, bflo(xB.y), acc[2]);
        acc[3] = fmaf(vB, bfhi(xB.y), acc[3]);
        acc[4] = fmaf(vB, bflo(xB.z), acc[4]);
        acc[5] = fmaf(vB, bfhi(xB.z), acc[5]);
        acc[6] = fmaf(vB, bflo(xB.w), acc[6]);
        acc[7] = fmaf(vB, bfhi(xB.w), acc[7]);
    }

    // reduce the 8 edge slots (slot bits are lane bits 3..5)
    #pragma unroll
    for (int k = 0; k < 8; ++k) {
        acc[k] += __shfl_xor(acc[k], 8);
        acc[k] += __shfl_xor(acc[k], 16);
        acc[k] += __shfl_xor(acc[k], 32);
    }

    if (lane < 8) {
        size_t o = (size_t)r * 8 + q;
        if (MODE == 0) {
            uint4 w;
            w.x = bfpack(acc[0], acc[1]);
            w.y = bfpack(acc[2], acc[3]);
            w.z = bfpack(acc[4], acc[5]);
            w.w = bfpack(acc[6], acc[7]);
            hbf[o] = w;
        } else {
            uint4 hb = src[o];   // src == hbf in MODE 1
            const float4* egop = (r < M_USERS)
                                 ? user4 + (size_t)r * 16
                                 : item4 + (size_t)(r - M_USERS) * 16;
            float4 e0 = egop[q * 2], e1 = egop[q * 2 + 1];
            float4 o0, o1;
            o0.x = e0.x + bflo(hb.x) + acc[0];
            o0.y = e0.y + bfhi(hb.x) + acc[1];
            o0.z = e0.z + bflo(hb.y) + acc[2];
            o0.w = e0.w + bfhi(hb.y) + acc[3];
            o1.x = e1.x + bflo(hb.z) + acc[4];
            o1.y = e1.y + bfhi(hb.z) + acc[5];
            o1.z = e1.z + bflo(hb.w) + acc[6];
            o1.w = e1.w + bfhi(hb.w) + acc[7];
            out4[(size_t)r * 16 + q * 2]     = o0;
            out4[(size_t)r * 16 + q * 2 + 1] = o1;
        }
    }
}

// ===========================================================================
// Fallback path: atomic scatter SPMM — used only if ws_size too small
// ===========================================================================
__global__ void init_ego(const float4* __restrict__ user,
                         const float4* __restrict__ item,
                         float4* __restrict__ out,
                         float4* __restrict__ h) {
    int i = blockIdx.x * blockDim.x + threadIdx.x;
    if (i >= NUM_NODES * 16) return;
    float4 v = (i < M_USERS * 16) ? user[i] : item[i - M_USERS * 16];
    out[i] = v;
    h[i] = make_float4(0.f, 0.f, 0.f, 0.f);
}

__global__ __launch_bounds__(256) void spmm_atomic(
        const int*   __restrict__ rows,
        const int*   __restrict__ cols,
        const float* __restrict__ vals,
        const float4* __restrict__ src,
        float*       __restrict__ dst) {
    int t = blockIdx.x * blockDim.x + threadIdx.x;
    if (t >= E_EDGES * 16) return;
    int e = t >> 4;
    int part = t & 15;
    int r = rows[e];
    int c = cols[e];
    float v = vals[e];
    float4 x = src[c * 16 + part];
    float* d = dst + (size_t)r * DIM + part * 4;
    atomicAdd(d + 0, x.x * v);
    atomicAdd(d + 1, x.y * v);
    atomicAdd(d + 2, x.z * v);
    atomicAdd(d + 3, x.w * v);
}

__global__ void add_inplace(float4* __restrict__ out, const float4* __restrict__ h) {
    int i = blockIdx.x * blockDim.x + threadIdx.x;
    if (i >= NUM_NODES * 16) return;
    float4 a = out[i], b = h[i];
    a.x += b.x; a.y += b.y; a.z += b.z; a.w += b.w;
    out[i] = a;
}

// ===========================================================================
// Fusion MLP via MFMA (unchanged from R5): one wave per 16-row group.
// ===========================================================================
__global__ __launch_bounds__(256) void fuse_mfma(
        float* __restrict__ acc,            // d_out: acc in, fused out
        const float* __restrict__ hg_user,
        const float* __restrict__ hg_item,
        const float* __restrict__ W1,       // (128, 64) row-major
        const float* __restrict__ b1,       // (64)
        const float* __restrict__ W2,       // (64, 2) row-major
        const float* __restrict__ b2,       // (2)
        int nGroups) {
    int tid  = threadIdx.x;
    int lane = tid & 63;
    int gid  = blockIdx.x * 4 + (tid >> 6);
    int lr   = lane & 15;     // A-row / B,C-col within tile
    int lg   = lane >> 4;     // k sub-group

    bf16x8 bfrag[16];
    #pragma unroll
    for (int kk = 0; kk < 4; ++kk)
        #pragma unroll
        for (int t = 0; t < 4; ++t)
            #pragma unroll
            for (int j = 0; j < 8; ++j)
                bfrag[kk * 4 + t][j] =
                    f2bf(W1[(kk * 32 + lg * 8 + j) * 64 + t * 16 + lr]);

    float b1v[4], w2a[4], w2b[4];
    #pragma unroll
    for (int t = 0; t < 4; ++t) {
        int c = t * 16 + lr;
        b1v[t] = b1[c];
        w2a[t] = W2[c * 2 + 0];
        w2b[t] = W2[c * 2 + 1];
    }
    float b2_0 = b2[0], b2_1 = b2[1];
    int srcLane = (lr >> 2) << 4;
    int sel = lr & 3;

    for (int g2 = 0; g2 < GPW; ++g2) {
        int grp = gid * GPW + g2;
        if (grp >= nGroups) break;
        int r = grp * 16 + lr;
        const float* f1p = acc + (size_t)r * DIM;
        const float* f2p = (r < M_USERS)
                           ? hg_user + (size_t)r * DIM
                           : hg_item + (size_t)(r - M_USERS) * DIM;

        float fr[4][8];
        #pragma unroll
        for (int kk = 0; kk < 4; ++kk) {
            const float* sp = (kk < 2) ? f1p : f2p;
            int cb = (kk & 1) * 32 + lg * 8;
            float4 u0 = *(const float4*)(sp + cb);
            float4 u1 = *(const float4*)(sp + cb + 4);
            float s = (kk < 2) ? (1.0f / 3.0f) : 1.0f;
            fr[kk][0] = u0.x * s; fr[kk][1] = u0.y * s;
            fr[kk][2] = u0.z * s; fr[kk][3] = u0.w * s;
            fr[kk][4] = u1.x * s; fr[kk][5] = u1.y * s;
            fr[kk][6] = u1.z * s; fr[kk][7] = u1.w * s;
        }

        f32x4 ct[4];
        #pragma unroll
        for (int t = 0; t < 4; ++t) ct[t] = (f32x4){0.f, 0.f, 0.f, 0.f};
        #pragma unroll
        for (int kk = 0; kk < 4; ++kk) {
            bf16x8 af;
            #pragma unroll
            for (int j = 0; j < 8; ++j) af[j] = f2bf(fr[kk][j]);
            #pragma unroll
            for (int t = 0; t < 4; ++t)
                ct[t] = __builtin_amdgcn_mfma_f32_16x16x32_bf16(
                            af, bfrag[kk * 4 + t], ct[t], 0, 0, 0);
        }

        float p0[4] = {0.f, 0.f, 0.f, 0.f};
        float p1[4] = {0.f, 0.f, 0.f, 0.f};
        #pragma unroll
        for (int t = 0; t < 4; ++t)
            #pragma unroll
            for (int q = 0; q < 4; ++q) {
                float hh = tanhf(ct[t][q] + b1v[t]);
                p0[q] = fmaf(hh, w2a[t], p0[q]);
                p1[q] = fmaf(hh, w2b[t], p1[q]);
            }
        #pragma unroll
        for (int q = 0; q < 4; ++q) {
            #pragma unroll
            for (int off = 1; off < 16; off <<= 1) {
                p0[q] += __shfl_xor(p0[q], off);
                p1[q] += __shfl_xor(p1[q], off);
            }
        }
        float w0q[4];
        #pragma unroll
        for (int q = 0; q < 4; ++q)
            w0q[q] = 1.0f / (1.0f + __expf((p1[q] + b2_1) - (p0[q] + b2_0)));

        float bq0 = __shfl(w0q[0], srcLane);
        float bq1 = __shfl(w0q[1], srcLane);
        float bq2 = __shfl(w0q[2], srcLane);
        float bq3 = __shfl(w0q[3], srcLane);
        float w0f = (sel == 0) ? bq0 : (sel == 1) ? bq1 : (sel == 2) ? bq2 : bq3;
        float w1f = 1.0f - w0f;

        float* outp = acc + (size_t)r * DIM;
        #pragma unroll
        for (int half = 0; half < 2; ++half) {
            int cb = half * 32 + lg * 8;
            float4 o0, o1;
            o0.x = w0f * fr[half][0] + w1f * fr[half + 2][0];
            o0.y = w0f * fr[half][1] + w1f * fr[half + 2][1];
            o0.z = w0f * fr[half][2] + w1f * fr[half + 2][2];
            o0.w = w0f * fr[half][3] + w1f * fr[half + 2][3];
            o1.x = w0f * fr[half][4] + w1f * fr[half + 2][4];
            o1.y = w0f * fr[half][5] + w1f * fr[half + 2][5];
            o1.z = w0f * fr[half][6] + w1f * fr[half + 2][6];
            o1.w = w0f * fr[half][7] + w1f * fr[half + 2][7];
            *(float4*)(outp + cb)     = o0;
            *(float4*)(outp + cb + 4) = o1;
        }
    }
}

// ===========================================================================
extern "C" void kernel_launch(void* const* d_in, const int* in_sizes, int n_in,
                              void* d_out, int out_size, void* d_ws, size_t ws_size,
                              hipStream_t stream) {
    const float* user_emb = (const float*)d_in[0];
    const float* item_emb = (const float*)d_in[1];
    const float* hg_user  = (const float*)d_in[2];
    const float* hg_item  = (const float*)d_in[3];
    const float* adj_vals = (const float*)d_in[4];
    const float* W1       = (const float*)d_in[5];
    const float* b1       = (const float*)d_in[6];
    const float* W2       = (const float*)d_in[7];
    const float* b2       = (const float*)d_in[8];
    const int*   adj_rows = (const int*)d_in[9];
    const int*   adj_cols = (const int*)d_in[10];

    float* out = (float*)d_out;

    // workspace layout (bandId last so Tier-2 is a prefix)
    char* ws = (char*)d_ws;
    size_t off = 0;
    uint4* egobf = (uint4*)(ws + off);    off += (size_t)NUM_NODES * 128;   // 38.4 MB
    uint4* hbf   = (uint4*)(ws + off);    off += (size_t)NUM_NODES * 128;   // 38.4 MB
    int* cnt    = (int*)(ws + off);       off += (size_t)NUM_NODES * 4;
    int* start  = (int*)(ws + off);       off += (size_t)NUM_NODES * 4;
    int* cursor = (int*)(ws + off);       off += (size_t)NUM_NODES * 4;
    int* part   = (int*)(ws + off);       off += ((size_t)NPART * 4 + 255) & ~255ull;
    int2* packed = (int2*)(ws + off);     off += (size_t)E_EDGES * 8;       // 32 MB
    const size_t needT2 = off;
    unsigned char* bandId = (unsigned char*)(ws + off); off += E_EDGES;     // 4 MB
    const size_t needT1 = off;

    const int nodeGrid = (NUM_NODES + 255) / 256;      // 1172
    const int edgeGrid = (E_EDGES + 255) / 256;        // 15625
    const int rowGrid  = (NUM_NODES + 3) / 4;          // 75000 (4 waves/block)
    const int egoGrid  = (NUM_NODES * 8 + 255) / 256;  // 9375

    if (ws_size >= needT2) {
        bool pref = (ws_size >= needT1);
        // ---- CSR build ----
        zero_counts<<<nodeGrid, 256, 0, stream>>>(cnt);
        hist_rows_band<<<edgeGrid, 256, 0, stream>>>(adj_rows, cnt,
                                                     pref ? bandId : nullptr);
        scan_blocks<<<NPART, 256, 0, stream>>>(cnt, start, part);
        scan_partials<<<1, 64, 0, stream>>>(part, NPART);
        add_offsets<<<nodeGrid, 256, 0, stream>>>(start, cursor, part);
        // bf16 ego table (independent of CSR chain)
        make_egobf<<<egoGrid, 256, 0, stream>>>(
            (const float4*)user_emb, (const float4*)item_emb, egobf);
        for (int b = 0; b < NBANDS; ++b) {
            if (pref)
                scatter_band_pref<<<edgeGrid, 256, 0, stream>>>(
                    adj_rows, adj_cols, adj_vals, bandId, cursor, packed, b);
            else
                scatter_band<<<edgeGrid, 256, 0, stream>>>(
                    adj_rows, adj_cols, adj_vals, cursor, packed,
                    b * BAND_ROWS, (b + 1) * BAND_ROWS);
        }
        // ---- SPMM passes over bf16 tables (cursor == start+cnt now) ----
        spmm_bf<0><<<rowGrid, 256, 0, stream>>>(start, cursor, packed,
                                                egobf, hbf,
                                                (const float4*)user_emb,
                                                (const float4*)item_emb,
                                                (float4*)out);
        spmm_bf<1><<<rowGrid, 256, 0, stream>>>(start, cursor, packed,
                                                hbf, nullptr,
                                                (const float4*)user_emb,
                                                (const float4*)item_emb,
                                                (float4*)out);
    } else {
        // ---- fallback: atomic path (reuses egobf+hbf region as fp32 h) ----
        float* h = (float*)ws;
        const int elems4Grid = (NUM_NODES * 16 + 255) / 256;
        const int spmmGrid   = (E_EDGES * 16 + 255) / 256;
        init_ego<<<elems4Grid, 256, 0, stream>>>(
            (const float4*)user_emb, (const float4*)item_emb,
            (float4*)out, (float4*)h);
        spmm_atomic<<<spmmGrid, 256, 0, stream>>>(
            adj_rows, adj_cols, adj_vals, (const float4*)out, h);
        add_inplace<<<elems4Grid, 256, 0, stream>>>((float4*)out, (const float4*)h);
        spmm_atomic<<<spmmGrid, 256, 0, stream>>>(
            adj_rows, adj_cols, adj_vals, (const float4*)h, out);
    }

    // ---- fusion MLP in-place on out (MFMA) ----
    const int fuseWaves  = (NGROUPS + GPW - 1) / GPW;          // 4688
    const int fuseBlocks = (fuseWaves + 3) / 4;                // 1172
    fuse_mfma<<<fuseBlocks, 256, 0, stream>>>(
        out, hg_user, hg_item, W1, b1, W2, b2, NGROUPS);
}

// Round 7
// 552.996 us; speedup vs baseline: 12.7940x; 1.3131x over previous
//
#include <hip/hip_runtime.h>
#include <hip/hip_bf16.h>

#define M_USERS   200000
#define N_ITEMS   100000
#define NUM_NODES 300000   // M + N
#define DIM       64
#define E_EDGES   4000000
#define NGROUPS   (NUM_NODES / 16)            // 18750 row-groups of 16
#define GPW       4                           // groups per wave in fuse

// two-level counting sort params
#define B2NB  256                              // number of bands
#define B2R   ((NUM_NODES + B2NB - 1) / B2NB)  // 1172 rows per band
#define SBLK  512                              // blocks for bcount/bscatter
#define EPB   ((E_EDGES + SBLK - 1) / SBLK)    // 7813 edges per block

typedef __attribute__((ext_vector_type(8))) short bf16x8;   // 8 bf16 (4 VGPRs)
typedef __attribute__((ext_vector_type(4))) float f32x4;    // 4 fp32

__device__ __forceinline__ short f2bf(float x) {
    __hip_bfloat16 h = __float2bfloat16(x);
    return *reinterpret_cast<short*>(&h);
}

// bf16 pair pack/unpack (RN-even rounding on pack)
__device__ __forceinline__ unsigned bfpack(float a, float b) {
    unsigned ua = __float_as_uint(a), ub = __float_as_uint(b);
    unsigned ra = (ua + 0x7fffu + ((ua >> 16) & 1u)) >> 16;
    unsigned rb = (ub + 0x7fffu + ((ub >> 16) & 1u)) >> 16;
    return ra | (rb << 16);
}
__device__ __forceinline__ float bflo(unsigned u) { return __uint_as_float(u << 16); }
__device__ __forceinline__ float bfhi(unsigned u) { return __uint_as_float(u & 0xffff0000u); }

// ===========================================================================
// Two-level counting sort build (no per-edge device atomics)
// ===========================================================================

__global__ void zero_small(int* __restrict__ bandTotal) {
    bandTotal[threadIdx.x] = 0;   // <<<1,256>>>
}

// level-1 count: LDS histogram over 256 bands, 256 global atomics per block
__global__ __launch_bounds__(256) void bcount(const int* __restrict__ rows,
                                              int* __restrict__ bandTotal) {
    __shared__ int bh[B2NB];
    int tid = threadIdx.x;
    bh[tid] = 0;
    __syncthreads();
    int e0 = blockIdx.x * EPB;
    int e1 = min(E_EDGES, e0 + EPB);
    for (int e = e0 + tid; e < e1; e += 256)
        atomicAdd(&bh[rows[e] / B2R], 1);
    __syncthreads();
    atomicAdd(&bandTotal[tid], bh[tid]);
}

// exclusive scan of 256 band totals -> bandBase, bandCursor (single wave)
__global__ void scan_small(const int* __restrict__ bandTotal,
                           int* __restrict__ bandBase,
                           int* __restrict__ bandCursor) {
    int lane = threadIdx.x;   // blockDim.x == 64
    int carry = 0;
    for (int base = 0; base < B2NB; base += 64) {
        int v = bandTotal[base + lane];
        int incl = v;
        #pragma unroll
        for (int off = 1; off < 64; off <<= 1) {
            int t = __shfl_up(incl, off);
            if (lane >= off) incl += t;
        }
        int excl = carry + incl - v;
        bandBase[base + lane]   = excl;
        bandCursor[base + lane] = excl;
        carry += __shfl(incl, 63);
    }
}

// level-1 scatter: band-group edges as (lr<<19|col, val); per-(block,band)
// reservation = 1 global atomic per band per block.
__global__ __launch_bounds__(256) void bscatter(const int* __restrict__ rows,
                                                const int* __restrict__ cols,
                                                const float* __restrict__ vals,
                                                int* __restrict__ bandCursor,
                                                unsigned* __restrict__ ek,
                                                float* __restrict__ ev) {
    __shared__ int bh[B2NB], bbase[B2NB], bcur[B2NB];
    int tid = threadIdx.x;
    bh[tid] = 0;
    __syncthreads();
    int e0 = blockIdx.x * EPB;
    int e1 = min(E_EDGES, e0 + EPB);
    for (int e = e0 + tid; e < e1; e += 256)
        atomicAdd(&bh[rows[e] / B2R], 1);
    __syncthreads();
    bbase[tid] = atomicAdd(&bandCursor[tid], bh[tid]);
    bcur[tid] = 0;
    __syncthreads();
    for (int e = e0 + tid; e < e1; e += 256) {
        int r = rows[e];
        int b = r / B2R;
        int lr = r - b * B2R;
        int ofs = atomicAdd(&bcur[b], 1);
        int pos = bbase[b] + ofs;
        ek[pos] = ((unsigned)lr << 19) | (unsigned)cols[e];
        ev[pos] = vals[e];
    }
}

// level-2: one block per band; LDS row-histogram + scan; emit start/endp and
// per-row-contiguous packed[] (all grouping atomics in LDS).
__global__ __launch_bounds__(256) void rsort(const int* __restrict__ bandBase,
                                             const int* __restrict__ bandTotal,
                                             const unsigned* __restrict__ ek,
                                             const float* __restrict__ ev,
                                             int* __restrict__ startp,
                                             int* __restrict__ endp,
                                             int2* __restrict__ packed) {
    __shared__ int hcnt[B2R], hexc[B2R], hcur[B2R];
    __shared__ int s[256];
    __shared__ int carryS;
    int b = blockIdx.x;
    int tid = threadIdx.x;
    int base = bandBase[b];
    int n = bandTotal[b];

    for (int i = tid; i < B2R; i += 256) hcnt[i] = 0;
    if (tid == 0) carryS = 0;
    __syncthreads();
    for (int k = tid; k < n; k += 256)
        atomicAdd(&hcnt[ek[base + k] >> 19], 1);
    __syncthreads();

    // exclusive scan of hcnt[0..B2R) in 5 chunks of 256
    #pragma unroll
    for (int c = 0; c < (B2R + 255) / 256; ++c) {
        int idx = c * 256 + tid;
        int v = (idx < B2R) ? hcnt[idx] : 0;
        s[tid] = v;
        __syncthreads();
        #pragma unroll
        for (int off = 1; off < 256; off <<= 1) {
            int t = (tid >= off) ? s[tid - off] : 0;
            __syncthreads();
            s[tid] += t;
            __syncthreads();
        }
        int excl = s[tid] - v + carryS;
        if (idx < B2R) { hexc[idx] = excl; hcur[idx] = excl; }
        __syncthreads();
        if (tid == 255) carryS += s[255];
        __syncthreads();
    }

    // emit CSR row ranges
    for (int i = tid; i < B2R; i += 256) {
        int r = b * B2R + i;
        if (r < NUM_NODES) {
            startp[r] = base + hexc[i];
            endp[r]   = base + hexc[i] + hcnt[i];
        }
    }
    __syncthreads();

    // scatter within band (LDS cursors)
    for (int k = tid; k < n; k += 256) {
        unsigned u = ek[base + k];
        int lr  = u >> 19;
        int col = u & 0x7FFFFu;
        int pos = base + atomicAdd(&hcur[lr], 1);
        packed[pos] = make_int2(col, __float_as_int(ev[base + k]));
    }
}

// ===========================================================================
// bf16 ego table build: 8 floats -> 8 bf16 (16B) per thread
// ===========================================================================
__global__ __launch_bounds__(256) void make_egobf(const float4* __restrict__ user,
                                                  const float4* __restrict__ item,
                                                  uint4* __restrict__ ego) {
    int c = blockIdx.x * blockDim.x + threadIdx.x;   // chunk of 8 floats
    if (c >= NUM_NODES * 8) return;
    const float4* src = (c < M_USERS * 8) ? user + (size_t)c * 2
                                          : item + ((size_t)c - M_USERS * 8) * 2;
    float4 u0 = src[0], u1 = src[1];
    uint4 w;
    w.x = bfpack(u0.x, u0.y);
    w.y = bfpack(u0.z, u0.w);
    w.z = bfpack(u1.x, u1.y);
    w.w = bfpack(u1.z, u1.w);
    ego[c] = w;
}

// ===========================================================================
// SPMM gather over bf16 tables: one wave per row; 8 edge slots x 8 lanes,
// each lane reads 16B (8 bf16) -> 16 edges in flight per iteration.
// MODE 0: hbf[r] = bf16( sum v * egobf[c] )
// MODE 1: out[r] = ego_fp32[r] + hbf[r] + sum v * hbf[c]   (fp32 out)
// ===========================================================================
template <int MODE>
__global__ __launch_bounds__(256) void spmm_bf(
        const int*  __restrict__ start,
        const int*  __restrict__ endp,
        const int2* __restrict__ packed,
        const uint4* __restrict__ src,     // bf16 table: 8 uint4 per row
        uint4* __restrict__ hbf,           // MODE 0 dest
        const float4* __restrict__ user4,  // MODE 1: fp32 ego
        const float4* __restrict__ item4,
        float4* __restrict__ out4) {
    int wave = threadIdx.x >> 6, lane = threadIdx.x & 63;
    int r = blockIdx.x * 4 + wave;
    if (r >= NUM_NODES) return;
    int s = start[r];
    int end = endp[r];
    int sub = lane >> 3;      // edge slot 0..7
    int q   = lane & 7;       // uint4 (8 bf16) index within the 128B row

    float acc[8] = {0.f, 0.f, 0.f, 0.f, 0.f, 0.f, 0.f, 0.f};

    for (int j = s; j < end; j += 16) {
        int iA = j + sub;
        int iB = j + 8 + sub;
        int2 pA = (iA < end) ? packed[iA] : make_int2(0, 0);
        int2 pB = (iB < end) ? packed[iB] : make_int2(0, 0);
        uint4 xA = src[(size_t)pA.x * 8 + q];
        uint4 xB = src[(size_t)pB.x * 8 + q];
        float vA = __int_as_float(pA.y);
        float vB = __int_as_float(pB.y);
        acc[0] = fmaf(vA, bflo(xA.x), acc[0]);
        acc[1] = fmaf(vA, bfhi(xA.x), acc[1]);
        acc[2] = fmaf(vA, bflo(xA.y), acc[2]);
        acc[3] = fmaf(vA, bfhi(xA.y), acc[3]);
        acc[4] = fmaf(vA, bflo(xA.z), acc[4]);
        acc[5] = fmaf(vA, bfhi(xA.z), acc[5]);
        acc[6] = fmaf(vA, bflo(xA.w), acc[6]);
        acc[7] = fmaf(vA, bfhi(xA.w), acc[7]);
        acc[0] = fmaf(vB, bflo(xB.x), acc[0]);
        acc[1] = fmaf(vB, bfhi(xB.x), acc[1]);
        acc[2] = fmaf(vB, bflo(xB.y), acc[2]);
        acc[3] = fmaf(vB, bfhi(xB.y), acc[3]);
        acc[4] = fmaf(vB, bflo(xB.z), acc[4]);
        acc[5] = fmaf(vB, bfhi(xB.z), acc[5]);
        acc[6] = fmaf(vB, bflo(xB.w), acc[6]);
        acc[7] = fmaf(vB, bfhi(xB.w), acc[7]);
    }

    #pragma unroll
    for (int k = 0; k < 8; ++k) {
        acc[k] += __shfl_xor(acc[k], 8);
        acc[k] += __shfl_xor(acc[k], 16);
        acc[k] += __shfl_xor(acc[k], 32);
    }

    if (lane < 8) {
        size_t o = (size_t)r * 8 + q;
        if (MODE == 0) {
            uint4 w;
            w.x = bfpack(acc[0], acc[1]);
            w.y = bfpack(acc[2], acc[3]);
            w.z = bfpack(acc[4], acc[5]);
            w.w = bfpack(acc[6], acc[7]);
            hbf[o] = w;
        } else {
            uint4 hb = src[o];   // src == hbf in MODE 1
            const float4* egop = (r < M_USERS)
                                 ? user4 + (size_t)r * 16
                                 : item4 + (size_t)(r - M_USERS) * 16;
            float4 e0 = egop[q * 2], e1 = egop[q * 2 + 1];
            float4 o0, o1;
            o0.x = e0.x + bflo(hb.x) + acc[0];
            o0.y = e0.y + bfhi(hb.x) + acc[1];
            o0.z = e0.z + bflo(hb.y) + acc[2];
            o0.w = e0.w + bfhi(hb.y) + acc[3];
            o1.x = e1.x + bflo(hb.z) + acc[4];
            o1.y = e1.y + bfhi(hb.z) + acc[5];
            o1.z = e1.z + bflo(hb.w) + acc[6];
            o1.w = e1.w + bfhi(hb.w) + acc[7];
            out4[(size_t)r * 16 + q * 2]     = o0;
            out4[(size_t)r * 16 + q * 2 + 1] = o1;
        }
    }
}

// ===========================================================================
// Fallback path: atomic scatter SPMM — used only if ws_size too small
// ===========================================================================
__global__ void init_ego(const float4* __restrict__ user,
                         const float4* __restrict__ item,
                         float4* __restrict__ out,
                         float4* __restrict__ h) {
    int i = blockIdx.x * blockDim.x + threadIdx.x;
    if (i >= NUM_NODES * 16) return;
    float4 v = (i < M_USERS * 16) ? user[i] : item[i - M_USERS * 16];
    out[i] = v;
    h[i] = make_float4(0.f, 0.f, 0.f, 0.f);
}

__global__ __launch_bounds__(256) void spmm_atomic(
        const int*   __restrict__ rows,
        const int*   __restrict__ cols,
        const float* __restrict__ vals,
        const float4* __restrict__ src,
        float*       __restrict__ dst) {
    int t = blockIdx.x * blockDim.x + threadIdx.x;
    if (t >= E_EDGES * 16) return;
    int e = t >> 4;
    int part = t & 15;
    int r = rows[e];
    int c = cols[e];
    float v = vals[e];
    float4 x = src[c * 16 + part];
    float* d = dst + (size_t)r * DIM + part * 4;
    atomicAdd(d + 0, x.x * v);
    atomicAdd(d + 1, x.y * v);
    atomicAdd(d + 2, x.z * v);
    atomicAdd(d + 3, x.w * v);
}

__global__ void add_inplace(float4* __restrict__ out, const float4* __restrict__ h) {
    int i = blockIdx.x * blockDim.x + threadIdx.x;
    if (i >= NUM_NODES * 16) return;
    float4 a = out[i], b = h[i];
    a.x += b.x; a.y += b.y; a.z += b.z; a.w += b.w;
    out[i] = a;
}

// ===========================================================================
// Fusion MLP via MFMA: one wave per 16-row group (GPW groups per wave).
// ===========================================================================
__global__ __launch_bounds__(256) void fuse_mfma(
        float* __restrict__ acc,            // d_out: acc in, fused out
        const float* __restrict__ hg_user,
        const float* __restrict__ hg_item,
        const float* __restrict__ W1,       // (128, 64) row-major
        const float* __restrict__ b1,       // (64)
        const float* __restrict__ W2,       // (64, 2) row-major
        const float* __restrict__ b2,       // (2)
        int nGroups) {
    int tid  = threadIdx.x;
    int lane = tid & 63;
    int gid  = blockIdx.x * 4 + (tid >> 6);
    int lr   = lane & 15;     // A-row / B,C-col within tile
    int lg   = lane >> 4;     // k sub-group

    bf16x8 bfrag[16];
    #pragma unroll
    for (int kk = 0; kk < 4; ++kk)
        #pragma unroll
        for (int t = 0; t < 4; ++t)
            #pragma unroll
            for (int j = 0; j < 8; ++j)
                bfrag[kk * 4 + t][j] =
                    f2bf(W1[(kk * 32 + lg * 8 + j) * 64 + t * 16 + lr]);

    float b1v[4], w2a[4], w2b[4];
    #pragma unroll
    for (int t = 0; t < 4; ++t) {
        int c = t * 16 + lr;
        b1v[t] = b1[c];
        w2a[t] = W2[c * 2 + 0];
        w2b[t] = W2[c * 2 + 1];
    }
    float b2_0 = b2[0], b2_1 = b2[1];
    int srcLane = (lr >> 2) << 4;
    int sel = lr & 3;

    for (int g2 = 0; g2 < GPW; ++g2) {
        int grp = gid * GPW + g2;
        if (grp >= nGroups) break;
        int r = grp * 16 + lr;
        const float* f1p = acc + (size_t)r * DIM;
        const float* f2p = (r < M_USERS)
                           ? hg_user + (size_t)r * DIM
                           : hg_item + (size_t)(r - M_USERS) * DIM;

        float fr[4][8];
        #pragma unroll
        for (int kk = 0; kk < 4; ++kk) {
            const float* sp = (kk < 2) ? f1p : f2p;
            int cb = (kk & 1) * 32 + lg * 8;
            float4 u0 = *(const float4*)(sp + cb);
            float4 u1 = *(const float4*)(sp + cb + 4);
            float s = (kk < 2) ? (1.0f / 3.0f) : 1.0f;
            fr[kk][0] = u0.x * s; fr[kk][1] = u0.y * s;
            fr[kk][2] = u0.z * s; fr[kk][3] = u0.w * s;
            fr[kk][4] = u1.x * s; fr[kk][5] = u1.y * s;
            fr[kk][6] = u1.z * s; fr[kk][7] = u1.w * s;
        }

        f32x4 ct[4];
        #pragma unroll
        for (int t = 0; t < 4; ++t) ct[t] = (f32x4){0.f, 0.f, 0.f, 0.f};
        #pragma unroll
        for (int kk = 0; kk < 4; ++kk) {
            bf16x8 af;
            #pragma unroll
            for (int j = 0; j < 8; ++j) af[j] = f2bf(fr[kk][j]);
            #pragma unroll
            for (int t = 0; t < 4; ++t)
                ct[t] = __builtin_amdgcn_mfma_f32_16x16x32_bf16(
                            af, bfrag[kk * 4 + t], ct[t], 0, 0, 0);
        }

        float p0[4] = {0.f, 0.f, 0.f, 0.f};
        float p1[4] = {0.f, 0.f, 0.f, 0.f};
        #pragma unroll
        for (int t = 0; t < 4; ++t)
            #pragma unroll
            for (int q = 0; q < 4; ++q) {
                float hh = tanhf(ct[t][q] + b1v[t]);
                p0[q] = fmaf(hh, w2a[t], p0[q]);
                p1[q] = fmaf(hh, w2b[t], p1[q]);
            }
        #pragma unroll
        for (int q = 0; q < 4; ++q) {
            #pragma unroll
            for (int off = 1; off < 16; off <<= 1) {
                p0[q] += __shfl_xor(p0[q], off);
                p1[q] += __shfl_xor(p1[q], off);
            }
        }
        float w0q[4];
        #pragma unroll
        for (int q = 0; q < 4; ++q)
            w0q[q] = 1.0f / (1.0f + __expf((p1[q] + b2_1) - (p0[q] + b2_0)));

        float bq0 = __shfl(w0q[0], srcLane);
        float bq1 = __shfl(w0q[1], srcLane);
        float bq2 = __shfl(w0q[2], srcLane);
        float bq3 = __shfl(w0q[3], srcLane);
        float w0f = (sel == 0) ? bq0 : (sel == 1) ? bq1 : (sel == 2) ? bq2 : bq3;
        float w1f = 1.0f - w0f;

        float* outp = acc + (size_t)r * DIM;
        #pragma unroll
        for (int half = 0; half < 2; ++half) {
            int cb = half * 32 + lg * 8;
            float4 o0, o1;
            o0.x = w0f * fr[half][0] + w1f * fr[half + 2][0];
            o0.y = w0f * fr[half][1] + w1f * fr[half + 2][1];
            o0.z = w0f * fr[half][2] + w1f * fr[half + 2][2];
            o0.w = w0f * fr[half][3] + w1f * fr[half + 2][3];
            o1.x = w0f * fr[half][4] + w1f * fr[half + 2][4];
            o1.y = w0f * fr[half][5] + w1f * fr[half + 2][5];
            o1.z = w0f * fr[half][6] + w1f * fr[half + 2][6];
            o1.w = w0f * fr[half][7] + w1f * fr[half + 2][7];
            *(float4*)(outp + cb)     = o0;
            *(float4*)(outp + cb + 4) = o1;
        }
    }
}

// ===========================================================================
extern "C" void kernel_launch(void* const* d_in, const int* in_sizes, int n_in,
                              void* d_out, int out_size, void* d_ws, size_t ws_size,
                              hipStream_t stream) {
    const float* user_emb = (const float*)d_in[0];
    const float* item_emb = (const float*)d_in[1];
    const float* hg_user  = (const float*)d_in[2];
    const float* hg_item  = (const float*)d_in[3];
    const float* adj_vals = (const float*)d_in[4];
    const float* W1       = (const float*)d_in[5];
    const float* b1       = (const float*)d_in[6];
    const float* W2       = (const float*)d_in[7];
    const float* b2       = (const float*)d_in[8];
    const int*   adj_rows = (const int*)d_in[9];
    const int*   adj_cols = (const int*)d_in[10];

    float* out = (float*)d_out;

    // workspace layout (ek/ev overlay hbf: dead once spmm_bf<0> runs)
    char* ws = (char*)d_ws;
    size_t off = 0;
    uint4* egobf = (uint4*)(ws + off);    off += (size_t)NUM_NODES * 128;   // 38.4 MB
    char*  hbfRegion = ws + off;          off += (size_t)NUM_NODES * 128;   // 38.4 MB
    uint4* hbf = (uint4*)hbfRegion;
    unsigned* ek = (unsigned*)hbfRegion;                                    // 16 MB
    float*    ev = (float*)(hbfRegion + (size_t)E_EDGES * 4);               // 16 MB
    int2* packed = (int2*)(ws + off);     off += (size_t)E_EDGES * 8;       // 32 MB
    int* startp = (int*)(ws + off);       off += (size_t)NUM_NODES * 4;
    int* endp   = (int*)(ws + off);       off += (size_t)NUM_NODES * 4;
    int* bandTotal  = (int*)(ws + off);   off += B2NB * 4;
    int* bandBase   = (int*)(ws + off);   off += B2NB * 4;
    int* bandCursor = (int*)(ws + off);   off += B2NB * 4;
    const size_t need = off;

    const int rowGrid = (NUM_NODES + 3) / 4;           // 75000 (4 waves/block)
    const int egoGrid = (NUM_NODES * 8 + 255) / 256;   // 9375

    if (ws_size >= need) {
        // ---- bf16 ego table (independent) ----
        make_egobf<<<egoGrid, 256, 0, stream>>>(
            (const float4*)user_emb, (const float4*)item_emb, egobf);
        // ---- two-level counting-sort CSR build ----
        zero_small<<<1, 256, 0, stream>>>(bandTotal);
        bcount<<<SBLK, 256, 0, stream>>>(adj_rows, bandTotal);
        scan_small<<<1, 64, 0, stream>>>(bandTotal, bandBase, bandCursor);
        bscatter<<<SBLK, 256, 0, stream>>>(adj_rows, adj_cols, adj_vals,
                                           bandCursor, ek, ev);
        rsort<<<B2NB, 256, 0, stream>>>(bandBase, bandTotal, ek, ev,
                                        startp, endp, packed);
        // ---- SPMM passes over bf16 tables ----
        spmm_bf<0><<<rowGrid, 256, 0, stream>>>(startp, endp, packed,
                                                egobf, hbf,
                                                (const float4*)user_emb,
                                                (const float4*)item_emb,
                                                (float4*)out);
        spmm_bf<1><<<rowGrid, 256, 0, stream>>>(startp, endp, packed,
                                                hbf, nullptr,
                                                (const float4*)user_emb,
                                                (const float4*)item_emb,
                                                (float4*)out);
    } else {
        // ---- fallback: atomic path (uses ws as fp32 h) ----
        float* h = (float*)ws;
        const int elems4Grid = (NUM_NODES * 16 + 255) / 256;
        const int spmmGrid   = (E_EDGES * 16 + 255) / 256;
        init_ego<<<elems4Grid, 256, 0, stream>>>(
            (const float4*)user_emb, (const float4*)item_emb,
            (float4*)out, (float4*)h);
        spmm_atomic<<<spmmGrid, 256, 0, stream>>>(
            adj_rows, adj_cols, adj_vals, (const float4*)out, h);
        add_inplace<<<elems4Grid, 256, 0, stream>>>((float4*)out, (const float4*)h);
        spmm_atomic<<<spmmGrid, 256, 0, stream>>>(
            adj_rows, adj_cols, adj_vals, (const float4*)h, out);
    }

    // ---- fusion MLP in-place on out (MFMA) ----
    const int fuseWaves  = (NGROUPS + GPW - 1) / GPW;          // 4688
    const int fuseBlocks = (fuseWaves + 3) / 4;                // 1172
    fuse_mfma<<<fuseBlocks, 256, 0, stream>>>(
        out, hg_user, hg_item, W1, b1, W2, b2, NGROUPS);
}

// Round 8
// 541.254 us; speedup vs baseline: 13.0716x; 1.0217x over previous
//
#include <hip/hip_runtime.h>
#include <hip/hip_bf16.h>

#define M_USERS   200000
#define N_ITEMS   100000
#define NUM_NODES 300000   // M + N
#define DIM       64
#define E_EDGES   4000000
#define NGROUPS   (NUM_NODES / 16)            // 18750 row-groups of 16
#define GPW       4                           // groups per wave in fuse

// two-level counting sort params
#define B2NB  256                              // number of bands
#define B2R   ((NUM_NODES + B2NB - 1) / B2NB)  // 1172 rows per band
#define SBLK  512                              // blocks for bcount/bscatter
#define EPB   ((E_EDGES + SBLK - 1) / SBLK)    // 7813 edges per block

typedef __attribute__((ext_vector_type(8))) short bf16x8;   // 8 bf16 (4 VGPRs)
typedef __attribute__((ext_vector_type(4))) float f32x4;    // 4 fp32
typedef __attribute__((ext_vector_type(2))) float f32x2;    // 2 fp32

__device__ __forceinline__ short f2bf(float x) {
    __hip_bfloat16 h = __float2bfloat16(x);
    return *reinterpret_cast<short*>(&h);
}

// bf16 pair pack/unpack (RN-even rounding on pack)
__device__ __forceinline__ unsigned bfpack(float a, float b) {
    unsigned ua = __float_as_uint(a), ub = __float_as_uint(b);
    unsigned ra = (ua + 0x7fffu + ((ua >> 16) & 1u)) >> 16;
    unsigned rb = (ub + 0x7fffu + ((ub >> 16) & 1u)) >> 16;
    return ra | (rb << 16);
}
__device__ __forceinline__ float bflo(unsigned u) { return __uint_as_float(u << 16); }
__device__ __forceinline__ float bfhi(unsigned u) { return __uint_as_float(u & 0xffff0000u); }

// fp8 e4m3 (OCP) packed HW converts — gfx942+/gfx950
template <bool HI>
__device__ __forceinline__ unsigned pk8(float a, float b, unsigned old) {
    return (unsigned)__builtin_amdgcn_cvt_pk_fp8_f32(a, b, (int)old, HI);
}
template <bool HI>
__device__ __forceinline__ f32x2 upk8(unsigned w) {
    return __builtin_amdgcn_cvt_pk_f32_fp8((int)w, HI);
}

// ===========================================================================
// Two-level counting sort build (no per-edge device atomics)
// ===========================================================================

__global__ void zero_small(int* __restrict__ bandTotal) {
    bandTotal[threadIdx.x] = 0;   // <<<1,256>>>
}

// level-1 count: LDS histogram over 256 bands, 256 global atomics per block
__global__ __launch_bounds__(256) void bcount(const int* __restrict__ rows,
                                              int* __restrict__ bandTotal) {
    __shared__ int bh[B2NB];
    int tid = threadIdx.x;
    bh[tid] = 0;
    __syncthreads();
    int e0 = blockIdx.x * EPB;
    int e1 = min(E_EDGES, e0 + EPB);
    for (int e = e0 + tid; e < e1; e += 256)
        atomicAdd(&bh[rows[e] / B2R], 1);
    __syncthreads();
    atomicAdd(&bandTotal[tid], bh[tid]);
}

// exclusive scan of 256 band totals -> bandBase, bandCursor (single wave)
__global__ void scan_small(const int* __restrict__ bandTotal,
                           int* __restrict__ bandBase,
                           int* __restrict__ bandCursor) {
    int lane = threadIdx.x;   // blockDim.x == 64
    int carry = 0;
    for (int base = 0; base < B2NB; base += 64) {
        int v = bandTotal[base + lane];
        int incl = v;
        #pragma unroll
        for (int off = 1; off < 64; off <<= 1) {
            int t = __shfl_up(incl, off);
            if (lane >= off) incl += t;
        }
        int excl = carry + incl - v;
        bandBase[base + lane]   = excl;
        bandCursor[base + lane] = excl;
        carry += __shfl(incl, 63);
    }
}

// level-1 scatter: band-group edges as (lr<<19|col, val); per-(block,band)
// reservation = 1 global atomic per band per block.
__global__ __launch_bounds__(256) void bscatter(const int* __restrict__ rows,
                                                const int* __restrict__ cols,
                                                const float* __restrict__ vals,
                                                int* __restrict__ bandCursor,
                                                unsigned* __restrict__ ek,
                                                float* __restrict__ ev) {
    __shared__ int bh[B2NB], bbase[B2NB], bcur[B2NB];
    int tid = threadIdx.x;
    bh[tid] = 0;
    __syncthreads();
    int e0 = blockIdx.x * EPB;
    int e1 = min(E_EDGES, e0 + EPB);
    for (int e = e0 + tid; e < e1; e += 256)
        atomicAdd(&bh[rows[e] / B2R], 1);
    __syncthreads();
    bbase[tid] = atomicAdd(&bandCursor[tid], bh[tid]);
    bcur[tid] = 0;
    __syncthreads();
    for (int e = e0 + tid; e < e1; e += 256) {
        int r = rows[e];
        int b = r / B2R;
        int lr = r - b * B2R;
        int ofs = atomicAdd(&bcur[b], 1);
        int pos = bbase[b] + ofs;
        ek[pos] = ((unsigned)lr << 19) | (unsigned)cols[e];
        ev[pos] = vals[e];
    }
}

// level-2: one block per band; LDS row-histogram + scan; emit start/endp and
// per-row-contiguous packed[] (all grouping atomics in LDS).
__global__ __launch_bounds__(256) void rsort(const int* __restrict__ bandBase,
                                             const int* __restrict__ bandTotal,
                                             const unsigned* __restrict__ ek,
                                             const float* __restrict__ ev,
                                             int* __restrict__ startp,
                                             int* __restrict__ endp,
                                             int2* __restrict__ packed) {
    __shared__ int hcnt[B2R], hexc[B2R], hcur[B2R];
    __shared__ int s[256];
    __shared__ int carryS;
    int b = blockIdx.x;
    int tid = threadIdx.x;
    int base = bandBase[b];
    int n = bandTotal[b];

    for (int i = tid; i < B2R; i += 256) hcnt[i] = 0;
    if (tid == 0) carryS = 0;
    __syncthreads();
    for (int k = tid; k < n; k += 256)
        atomicAdd(&hcnt[ek[base + k] >> 19], 1);
    __syncthreads();

    // exclusive scan of hcnt[0..B2R) in chunks of 256
    #pragma unroll
    for (int c = 0; c < (B2R + 255) / 256; ++c) {
        int idx = c * 256 + tid;
        int v = (idx < B2R) ? hcnt[idx] : 0;
        s[tid] = v;
        __syncthreads();
        #pragma unroll
        for (int off = 1; off < 256; off <<= 1) {
            int t = (tid >= off) ? s[tid - off] : 0;
            __syncthreads();
            s[tid] += t;
            __syncthreads();
        }
        int excl = s[tid] - v + carryS;
        if (idx < B2R) { hexc[idx] = excl; hcur[idx] = excl; }
        __syncthreads();
        if (tid == 255) carryS += s[255];
        __syncthreads();
    }

    // emit CSR row ranges
    for (int i = tid; i < B2R; i += 256) {
        int r = b * B2R + i;
        if (r < NUM_NODES) {
            startp[r] = base + hexc[i];
            endp[r]   = base + hexc[i] + hcnt[i];
        }
    }
    __syncthreads();

    // scatter within band (LDS cursors)
    for (int k = tid; k < n; k += 256) {
        unsigned u = ek[base + k];
        int lr  = u >> 19;
        int col = u & 0x7FFFFu;
        int pos = base + atomicAdd(&hcur[lr], 1);
        packed[pos] = make_int2(col, __float_as_int(ev[base + k]));
    }
}

// ===========================================================================
// fp8 ego table build: 8 floats -> 8 fp8 (8B uint2) per thread
// ===========================================================================
__global__ __launch_bounds__(256) void make_ego8(const float4* __restrict__ user,
                                                 const float4* __restrict__ item,
                                                 uint2* __restrict__ ego8) {
    int c = blockIdx.x * blockDim.x + threadIdx.x;   // chunk of 8 floats
    if (c >= NUM_NODES * 8) return;
    const float4* src = (c < M_USERS * 8) ? user + (size_t)c * 2
                                          : item + ((size_t)c - M_USERS * 8) * 2;
    float4 u0 = src[0], u1 = src[1];
    unsigned wx = pk8<false>(u0.x, u0.y, 0u);
    wx = pk8<true>(u0.z, u0.w, wx);
    unsigned wy = pk8<false>(u1.x, u1.y, 0u);
    wy = pk8<true>(u1.z, u1.w, wy);
    ego8[c] = make_uint2(wx, wy);
}

// ===========================================================================
// SPMM gather over fp8 tables: one wave per row; 8 edge slots x 8 lanes,
// each lane reads 8B (8 fp8) -> row = ONE 64B line, 16 edges in flight.
// MODE 0: gather ego8; write h as bf16 (hbf) + fp8 (h8)
// MODE 1: gather h8; out[r] = ego_fp32[r] + bf16(hbf[r]) + sum v * h8[c]
// ===========================================================================
template <int MODE>
__global__ __launch_bounds__(256) void spmm_f8(
        const int*  __restrict__ start,
        const int*  __restrict__ endp,
        const int2* __restrict__ packed,
        const uint2* __restrict__ gtab,    // fp8 gather table (ego8 / h8)
        uint4* __restrict__ hbf,           // MODE0: out; MODE1: direct-term in
        uint2* __restrict__ h8,            // MODE0: fp8 h out
        const float4* __restrict__ user4,  // MODE1: fp32 ego
        const float4* __restrict__ item4,
        float4* __restrict__ out4) {
    int wave = threadIdx.x >> 6, lane = threadIdx.x & 63;
    int r = blockIdx.x * 4 + wave;
    if (r >= NUM_NODES) return;
    int s = start[r];
    int end = endp[r];
    int sub = lane >> 3;      // edge slot 0..7
    int q   = lane & 7;       // uint2 (8 fp8) index within the 64B row

    float acc[8] = {0.f, 0.f, 0.f, 0.f, 0.f, 0.f, 0.f, 0.f};

    for (int j = s; j < end; j += 16) {
        int iA = j + sub;
        int iB = j + 8 + sub;
        int2 pA = (iA < end) ? packed[iA] : make_int2(0, 0);
        int2 pB = (iB < end) ? packed[iB] : make_int2(0, 0);
        uint2 xA = gtab[(size_t)pA.x * 8 + q];
        uint2 xB = gtab[(size_t)pB.x * 8 + q];
        float vA = __int_as_float(pA.y);
        float vB = __int_as_float(pB.y);
        f32x2 a01 = upk8<false>(xA.x), a23 = upk8<true>(xA.x);
        f32x2 a45 = upk8<false>(xA.y), a67 = upk8<true>(xA.y);
        acc[0] = fmaf(vA, a01.x, acc[0]);
        acc[1] = fmaf(vA, a01.y, acc[1]);
        acc[2] = fmaf(vA, a23.x, acc[2]);
        acc[3] = fmaf(vA, a23.y, acc[3]);
        acc[4] = fmaf(vA, a45.x, acc[4]);
        acc[5] = fmaf(vA, a45.y, acc[5]);
        acc[6] = fmaf(vA, a67.x, acc[6]);
        acc[7] = fmaf(vA, a67.y, acc[7]);
        f32x2 b01 = upk8<false>(xB.x), b23 = upk8<true>(xB.x);
        f32x2 b45 = upk8<false>(xB.y), b67 = upk8<true>(xB.y);
        acc[0] = fmaf(vB, b01.x, acc[0]);
        acc[1] = fmaf(vB, b01.y, acc[1]);
        acc[2] = fmaf(vB, b23.x, acc[2]);
        acc[3] = fmaf(vB, b23.y, acc[3]);
        acc[4] = fmaf(vB, b45.x, acc[4]);
        acc[5] = fmaf(vB, b45.y, acc[5]);
        acc[6] = fmaf(vB, b67.x, acc[6]);
        acc[7] = fmaf(vB, b67.y, acc[7]);
    }

    // reduce the 8 edge slots (slot bits are lane bits 3..5)
    #pragma unroll
    for (int k = 0; k < 8; ++k) {
        acc[k] += __shfl_xor(acc[k], 8);
        acc[k] += __shfl_xor(acc[k], 16);
        acc[k] += __shfl_xor(acc[k], 32);
    }

    if (lane < 8) {
        size_t o = (size_t)r * 8 + q;
        if (MODE == 0) {
            uint4 w;
            w.x = bfpack(acc[0], acc[1]);
            w.y = bfpack(acc[2], acc[3]);
            w.z = bfpack(acc[4], acc[5]);
            w.w = bfpack(acc[6], acc[7]);
            hbf[o] = w;
            unsigned wx = pk8<false>(acc[0], acc[1], 0u);
            wx = pk8<true>(acc[2], acc[3], wx);
            unsigned wy = pk8<false>(acc[4], acc[5], 0u);
            wy = pk8<true>(acc[6], acc[7], wy);
            h8[o] = make_uint2(wx, wy);
        } else {
            uint4 hb = hbf[o];   // bf16 h1 direct term (streamed)
            const float4* egop = (r < M_USERS)
                                 ? user4 + (size_t)r * 16
                                 : item4 + (size_t)(r - M_USERS) * 16;
            float4 e0 = egop[q * 2], e1 = egop[q * 2 + 1];
            float4 o0, o1;
            o0.x = e0.x + bflo(hb.x) + acc[0];
            o0.y = e0.y + bfhi(hb.x) + acc[1];
            o0.z = e0.z + bflo(hb.y) + acc[2];
            o0.w = e0.w + bfhi(hb.y) + acc[3];
            o1.x = e1.x + bflo(hb.z) + acc[4];
            o1.y = e1.y + bfhi(hb.z) + acc[5];
            o1.z = e1.z + bflo(hb.w) + acc[6];
            o1.w = e1.w + bfhi(hb.w) + acc[7];
            out4[(size_t)r * 16 + q * 2]     = o0;
            out4[(size_t)r * 16 + q * 2 + 1] = o1;
        }
    }
}

// ===========================================================================
// Fallback path: atomic scatter SPMM — used only if ws_size too small
// ===========================================================================
__global__ void init_ego(const float4* __restrict__ user,
                         const float4* __restrict__ item,
                         float4* __restrict__ out,
                         float4* __restrict__ h) {
    int i = blockIdx.x * blockDim.x + threadIdx.x;
    if (i >= NUM_NODES * 16) return;
    float4 v = (i < M_USERS * 16) ? user[i] : item[i - M_USERS * 16];
    out[i] = v;
    h[i] = make_float4(0.f, 0.f, 0.f, 0.f);
}

__global__ __launch_bounds__(256) void spmm_atomic(
        const int*   __restrict__ rows,
        const int*   __restrict__ cols,
        const float* __restrict__ vals,
        const float4* __restrict__ src,
        float*       __restrict__ dst) {
    int t = blockIdx.x * blockDim.x + threadIdx.x;
    if (t >= E_EDGES * 16) return;
    int e = t >> 4;
    int part = t & 15;
    int r = rows[e];
    int c = cols[e];
    float v = vals[e];
    float4 x = src[c * 16 + part];
    float* d = dst + (size_t)r * DIM + part * 4;
    atomicAdd(d + 0, x.x * v);
    atomicAdd(d + 1, x.y * v);
    atomicAdd(d + 2, x.z * v);
    atomicAdd(d + 3, x.w * v);
}

__global__ void add_inplace(float4* __restrict__ out, const float4* __restrict__ h) {
    int i = blockIdx.x * blockDim.x + threadIdx.x;
    if (i >= NUM_NODES * 16) return;
    float4 a = out[i], b = h[i];
    a.x += b.x; a.y += b.y; a.z += b.z; a.w += b.w;
    out[i] = a;
}

// ===========================================================================
// Fusion MLP via MFMA: one wave per 16-row group (GPW groups per wave).
// ===========================================================================
__global__ __launch_bounds__(256) void fuse_mfma(
        float* __restrict__ acc,            // d_out: acc in, fused out
        const float* __restrict__ hg_user,
        const float* __restrict__ hg_item,
        const float* __restrict__ W1,       // (128, 64) row-major
        const float* __restrict__ b1,       // (64)
        const float* __restrict__ W2,       // (64, 2) row-major
        const float* __restrict__ b2,       // (2)
        int nGroups) {
    int tid  = threadIdx.x;
    int lane = tid & 63;
    int gid  = blockIdx.x * 4 + (tid >> 6);
    int lr   = lane & 15;     // A-row / B,C-col within tile
    int lg   = lane >> 4;     // k sub-group

    bf16x8 bfrag[16];
    #pragma unroll
    for (int kk = 0; kk < 4; ++kk)
        #pragma unroll
        for (int t = 0; t < 4; ++t)
            #pragma unroll
            for (int j = 0; j < 8; ++j)
                bfrag[kk * 4 + t][j] =
                    f2bf(W1[(kk * 32 + lg * 8 + j) * 64 + t * 16 + lr]);

    float b1v[4], w2a[4], w2b[4];
    #pragma unroll
    for (int t = 0; t < 4; ++t) {
        int c = t * 16 + lr;
        b1v[t] = b1[c];
        w2a[t] = W2[c * 2 + 0];
        w2b[t] = W2[c * 2 + 1];
    }
    float b2_0 = b2[0], b2_1 = b2[1];
    int srcLane = (lr >> 2) << 4;
    int sel = lr & 3;

    for (int g2 = 0; g2 < GPW; ++g2) {
        int grp = gid * GPW + g2;
        if (grp >= nGroups) break;
        int r = grp * 16 + lr;
        const float* f1p = acc + (size_t)r * DIM;
        const float* f2p = (r < M_USERS)
                           ? hg_user + (size_t)r * DIM
                           : hg_item + (size_t)(r - M_USERS) * DIM;

        float fr[4][8];
        #pragma unroll
        for (int kk = 0; kk < 4; ++kk) {
            const float* sp = (kk < 2) ? f1p : f2p;
            int cb = (kk & 1) * 32 + lg * 8;
            float4 u0 = *(const float4*)(sp + cb);
            float4 u1 = *(const float4*)(sp + cb + 4);
            float s = (kk < 2) ? (1.0f / 3.0f) : 1.0f;
            fr[kk][0] = u0.x * s; fr[kk][1] = u0.y * s;
            fr[kk][2] = u0.z * s; fr[kk][3] = u0.w * s;
            fr[kk][4] = u1.x * s; fr[kk][5] = u1.y * s;
            fr[kk][6] = u1.z * s; fr[kk][7] = u1.w * s;
        }

        f32x4 ct[4];
        #pragma unroll
        for (int t = 0; t < 4; ++t) ct[t] = (f32x4){0.f, 0.f, 0.f, 0.f};
        #pragma unroll
        for (int kk = 0; kk < 4; ++kk) {
            bf16x8 af;
            #pragma unroll
            for (int j = 0; j < 8; ++j) af[j] = f2bf(fr[kk][j]);
            #pragma unroll
            for (int t = 0; t < 4; ++t)
                ct[t] = __builtin_amdgcn_mfma_f32_16x16x32_bf16(
                            af, bfrag[kk * 4 + t], ct[t], 0, 0, 0);
        }

        float p0[4] = {0.f, 0.f, 0.f, 0.f};
        float p1[4] = {0.f, 0.f, 0.f, 0.f};
        #pragma unroll
        for (int t = 0; t < 4; ++t)
            #pragma unroll
            for (int q = 0; q < 4; ++q) {
                float hh = tanhf(ct[t][q] + b1v[t]);
                p0[q] = fmaf(hh, w2a[t], p0[q]);
                p1[q] = fmaf(hh, w2b[t], p1[q]);
            }
        #pragma unroll
        for (int q = 0; q < 4; ++q) {
            #pragma unroll
            for (int off = 1; off < 16; off <<= 1) {
                p0[q] += __shfl_xor(p0[q], off);
                p1[q] += __shfl_xor(p1[q], off);
            }
        }
        float w0q[4];
        #pragma unroll
        for (int q = 0; q < 4; ++q)
            w0q[q] = 1.0f / (1.0f + __expf((p1[q] + b2_1) - (p0[q] + b2_0)));

        float bq0 = __shfl(w0q[0], srcLane);
        float bq1 = __shfl(w0q[1], srcLane);
        float bq2 = __shfl(w0q[2], srcLane);
        float bq3 = __shfl(w0q[3], srcLane);
        float w0f = (sel == 0) ? bq0 : (sel == 1) ? bq1 : (sel == 2) ? bq2 : bq3;
        float w1f = 1.0f - w0f;

        float* outp = acc + (size_t)r * DIM;
        #pragma unroll
        for (int half = 0; half < 2; ++half) {
            int cb = half * 32 + lg * 8;
            float4 o0, o1;
            o0.x = w0f * fr[half][0] + w1f * fr[half + 2][0];
            o0.y = w0f * fr[half][1] + w1f * fr[half + 2][1];
            o0.z = w0f * fr[half][2] + w1f * fr[half + 2][2];
            o0.w = w0f * fr[half][3] + w1f * fr[half + 2][3];
            o1.x = w0f * fr[half][4] + w1f * fr[half + 2][4];
            o1.y = w0f * fr[half][5] + w1f * fr[half + 2][5];
            o1.z = w0f * fr[half][6] + w1f * fr[half + 2][6];
            o1.w = w0f * fr[half][7] + w1f * fr[half + 2][7];
            *(float4*)(outp + cb)     = o0;
            *(float4*)(outp + cb + 4) = o1;
        }
    }
}

// ===========================================================================
extern "C" void kernel_launch(void* const* d_in, const int* in_sizes, int n_in,
                              void* d_out, int out_size, void* d_ws, size_t ws_size,
                              hipStream_t stream) {
    const float* user_emb = (const float*)d_in[0];
    const float* item_emb = (const float*)d_in[1];
    const float* hg_user  = (const float*)d_in[2];
    const float* hg_item  = (const float*)d_in[3];
    const float* adj_vals = (const float*)d_in[4];
    const float* W1       = (const float*)d_in[5];
    const float* b1       = (const float*)d_in[6];
    const float* W2       = (const float*)d_in[7];
    const float* b2       = (const float*)d_in[8];
    const int*   adj_rows = (const int*)d_in[9];
    const int*   adj_cols = (const int*)d_in[10];

    float* out = (float*)d_out;

    // workspace layout (ek/ev overlay hbf: ek/ev dead after rsort, hbf
    // written first by spmm_f8<0>)
    char* ws = (char*)d_ws;
    size_t off = 0;
    uint2* ego8 = (uint2*)(ws + off);     off += (size_t)NUM_NODES * 64;    // 19.2 MB
    uint2* h8   = (uint2*)(ws + off);     off += (size_t)NUM_NODES * 64;    // 19.2 MB
    char*  hbfRegion = ws + off;          off += (size_t)NUM_NODES * 128;   // 38.4 MB
    uint4* hbf = (uint4*)hbfRegion;
    unsigned* ek = (unsigned*)hbfRegion;                                    // 16 MB
    float*    ev = (float*)(hbfRegion + (size_t)E_EDGES * 4);               // 16 MB
    int2* packed = (int2*)(ws + off);     off += (size_t)E_EDGES * 8;       // 32 MB
    int* startp = (int*)(ws + off);       off += (size_t)NUM_NODES * 4;
    int* endp   = (int*)(ws + off);       off += (size_t)NUM_NODES * 4;
    int* bandTotal  = (int*)(ws + off);   off += B2NB * 4;
    int* bandBase   = (int*)(ws + off);   off += B2NB * 4;
    int* bandCursor = (int*)(ws + off);   off += B2NB * 4;
    const size_t need = off;

    const int rowGrid = (NUM_NODES + 3) / 4;           // 75000 (4 waves/block)
    const int egoGrid = (NUM_NODES * 8 + 255) / 256;   // 9375

    if (ws_size >= need) {
        // ---- fp8 ego table (independent of CSR chain) ----
        make_ego8<<<egoGrid, 256, 0, stream>>>(
            (const float4*)user_emb, (const float4*)item_emb, ego8);
        // ---- two-level counting-sort CSR build ----
        zero_small<<<1, 256, 0, stream>>>(bandTotal);
        bcount<<<SBLK, 256, 0, stream>>>(adj_rows, bandTotal);
        scan_small<<<1, 64, 0, stream>>>(bandTotal, bandBase, bandCursor);
        bscatter<<<SBLK, 256, 0, stream>>>(adj_rows, adj_cols, adj_vals,
                                           bandCursor, ek, ev);
        rsort<<<B2NB, 256, 0, stream>>>(bandBase, bandTotal, ek, ev,
                                        startp, endp, packed);
        // ---- SPMM passes over fp8 tables ----
        spmm_f8<0><<<rowGrid, 256, 0, stream>>>(startp, endp, packed,
                                                ego8, hbf, h8,
                                                (const float4*)user_emb,
                                                (const float4*)item_emb,
                                                (float4*)out);
        spmm_f8<1><<<rowGrid, 256, 0, stream>>>(startp, endp, packed,
                                                h8, hbf, nullptr,
                                                (const float4*)user_emb,
                                                (const float4*)item_emb,
                                                (float4*)out);
    } else {
        // ---- fallback: atomic path (uses ws as fp32 h) ----
        float* h = (float*)ws;
        const int elems4Grid = (NUM_NODES * 16 + 255) / 256;
        const int spmmGrid   = (E_EDGES * 16 + 255) / 256;
        init_ego<<<elems4Grid, 256, 0, stream>>>(
            (const float4*)user_emb, (const float4*)item_emb,
            (float4*)out, (float4*)h);
        spmm_atomic<<<spmmGrid, 256, 0, stream>>>(
            adj_rows, adj_cols, adj_vals, (const float4*)out, h);
        add_inplace<<<elems4Grid, 256, 0, stream>>>((float4*)out, (const float4*)h);
        spmm_atomic<<<spmmGrid, 256, 0, stream>>>(
            adj_rows, adj_cols, adj_vals, (const float4*)h, out);
    }

    // ---- fusion MLP in-place on out (MFMA) ----
    const int fuseWaves  = (NGROUPS + GPW - 1) / GPW;          // 4688
    const int fuseBlocks = (fuseWaves + 3) / 4;                // 1172
    fuse_mfma<<<fuseBlocks, 256, 0, stream>>>(
        out, hg_user, hg_item, W1, b1, W2, b2, NGROUPS);
}